// Round 1
// baseline (1122.406 us; speedup 1.0000x reference)
//
#include <hip/hip_runtime.h>
#include <hip/hip_bf16.h>
#include <math.h>

#define NN 50000
#define EE 800000
#define EP 850000   /* EE + NN self loops */
#define NEG 0.2f

__device__ inline void atomicMaxF(float* addr, float val) {
    if (val >= 0.f) atomicMax((int*)addr, __float_as_int(val));
    else            atomicMin((unsigned int*)addr, __float_as_uint(val));
}

// ---------------- init: zeros, -inf maxes, bias-broadcast outputs ----------------
__global__ void k_init(float* deg, float* asum, float* m1, float* s1,
                       float* out1, const float* __restrict__ b1,
                       float* m2, float* s2, float* dout, const float* __restrict__ b2) {
    int i = blockIdx.x * 256 + threadIdx.x;
    if (i < NN * 128) out1[i] = b1[i & 127];
    if (i < NN * 32)  dout[i] = b2[i & 31];
    if (i < NN * 4)   { m1[i] = -INFINITY; s1[i] = 0.f; }
    if (i < NN)       { deg[i] = 0.f; asum[i] = 0.f; m2[i] = -INFINITY; s2[i] = 0.f; }
}

// ---------------- edge-scalar constants ce1[4], ce2 ----------------
__global__ void k_const(const float* __restrict__ We1, const float* __restrict__ ae1,
                        const float* __restrict__ We2, const float* __restrict__ ae2,
                        float* cbuf) {
    int j = threadIdx.x;               // 128 threads
    float p = We1[j] * ae1[j];
    #pragma unroll
    for (int m = 16; m >= 1; m >>= 1) p += __shfl_xor(p, m);
    if ((j & 31) == 0) cbuf[j >> 5] = p;
    if (j < 32) {
        float q = We2[j] * ae2[j];
        #pragma unroll
        for (int m = 16; m >= 1; m >>= 1) q += __shfl_xor(q, m);
        if (j == 0) cbuf[4] = q;
    }
}

// ---------------- degree + incoming edge_attr sum ----------------
__global__ void k_deg(const int* __restrict__ ei, const float* __restrict__ eattr,
                      float* deg, float* asum) {
    int e = blockIdx.x * 256 + threadIdx.x;
    if (e >= EE) return;
    int d = ei[EE + e];
    atomicAdd(&deg[d], 1.f);
    atomicAdd(&asum[d], eattr[e]);
}

// ---------------- h1 = x @ W1  [N,128]; per-head att dots ----------------
__global__ void k_h1(const float* __restrict__ x, const float* __restrict__ W1,
                     const float* __restrict__ as1, const float* __restrict__ ad1,
                     float* h1, float* asrc1, float* adst1) {
    __shared__ float sx[4][128];
    int j = threadIdx.x;               // 128 threads, j = output column
    int base = blockIdx.x * 16;
    int h = j >> 5;
    float es = as1[j];                 // att_src1 flat [h*32+c]
    float ed = ad1[j];
    for (int it = 0; it < 4; ++it) {
        int n0 = base + it * 4;
        __syncthreads();
        #pragma unroll
        for (int r = 0; r < 4; ++r) {
            int n = n0 + r;
            sx[r][j] = (n < NN) ? x[(size_t)n * 128 + j] : 0.f;
        }
        __syncthreads();
        float a0 = 0.f, a1 = 0.f, a2 = 0.f, a3 = 0.f;
        #pragma unroll 8
        for (int k = 0; k < 128; ++k) {
            float w = W1[k * 128 + j];
            a0 += sx[0][k] * w; a1 += sx[1][k] * w;
            a2 += sx[2][k] * w; a3 += sx[3][k] * w;
        }
        float accs[4] = {a0, a1, a2, a3};
        #pragma unroll
        for (int r = 0; r < 4; ++r) {
            int n = n0 + r;
            float v = accs[r];
            float ps = v * es, pd = v * ed;
            #pragma unroll
            for (int m = 16; m >= 1; m >>= 1) { ps += __shfl_xor(ps, m); pd += __shfl_xor(pd, m); }
            if (n < NN) {
                h1[(size_t)n * 128 + j] = v;
                if ((j & 31) == 0) { asrc1[n * 4 + h] = ps; adst1[n * 4 + h] = pd; }
            }
        }
    }
}

// ---------------- layer-1 logits + segment max ----------------
__global__ void k_logit1(const int* __restrict__ ei, const float* __restrict__ eattr,
                         const float* __restrict__ deg, const float* __restrict__ asum,
                         const float* __restrict__ asrc1, const float* __restrict__ adst1,
                         const float* __restrict__ cbuf, float* logit1, float* m1) {
    int e = blockIdx.x * 256 + threadIdx.x;
    if (e >= EP) return;
    int s, d; float a;
    if (e < EE) { s = ei[e]; d = ei[EE + e]; a = eattr[e]; }
    else        { int n = e - EE; s = n; d = n; a = asum[n] / fmaxf(deg[n], 1.f); }
    const float4 vs = *(const float4*)&asrc1[s * 4];
    const float4 vd = *(const float4*)&adst1[d * 4];
    float z[4];
    z[0] = vs.x + vd.x + a * cbuf[0];
    z[1] = vs.y + vd.y + a * cbuf[1];
    z[2] = vs.z + vd.z + a * cbuf[2];
    z[3] = vs.w + vd.w + a * cbuf[3];
    #pragma unroll
    for (int hh = 0; hh < 4; ++hh) {
        z[hh] = z[hh] > 0.f ? z[hh] : NEG * z[hh];
        atomicMaxF(&m1[d * 4 + hh], z[hh]);
    }
    float4 o; o.x = z[0]; o.y = z[1]; o.z = z[2]; o.w = z[3];
    *(float4*)&logit1[(size_t)e * 4] = o;
}

// ---------------- layer-1 exp + segment sum ----------------
__global__ void k_exp1(const int* __restrict__ ei, float* logit1,
                       const float* __restrict__ m1, float* s1) {
    int e = blockIdx.x * 256 + threadIdx.x;
    if (e >= EP) return;
    int d = (e < EE) ? ei[EE + e] : (e - EE);
    float4 l = *(float4*)&logit1[(size_t)e * 4];
    const float4 mm = *(const float4*)&m1[d * 4];
    l.x = expf(l.x - mm.x); l.y = expf(l.y - mm.y);
    l.z = expf(l.z - mm.z); l.w = expf(l.w - mm.w);
    *(float4*)&logit1[(size_t)e * 4] = l;
    atomicAdd(&s1[d * 4 + 0], l.x);
    atomicAdd(&s1[d * 4 + 1], l.y);
    atomicAdd(&s1[d * 4 + 2], l.z);
    atomicAdd(&s1[d * 4 + 3], l.w);
}

// ---------------- layer-1 normalize: logit1 <- ex / s1[dst] ----------------
__global__ void k_norm1(const int* __restrict__ ei, float* logit1, const float* __restrict__ s1) {
    int e = blockIdx.x * 256 + threadIdx.x;
    if (e >= EP) return;
    int d = (e < EE) ? ei[EE + e] : (e - EE);
    float4 v = *(float4*)&logit1[(size_t)e * 4];
    const float4 sm = *(const float4*)&s1[d * 4];
    v.x /= sm.x; v.y /= sm.y; v.z /= sm.z; v.w /= sm.w;
    *(float4*)&logit1[(size_t)e * 4] = v;
}

// ---------------- layer-1 scatter aggregate (2 edges / 256-thread block) ----------------
__global__ void k_agg1(const int* __restrict__ ei, const float* __restrict__ w1,
                       const float* __restrict__ h1, float* out1) {
    int t = blockIdx.x * 256 + threadIdx.x;
    int e = t >> 7;
    int j = t & 127;
    if (e >= EP) return;
    int s, d;
    if (e < EE) { s = ei[e]; d = ei[EE + e]; } else { s = e - EE; d = s; }
    float w = w1[(size_t)e * 4 + (j >> 5)];
    atomicAdd(&out1[(size_t)d * 128 + j], w * h1[(size_t)s * 128 + j]);
}

// ---------------- h2 = elu(out1 + b1) @ W2  [N,32]; layer-2 att dots ----------------
__global__ void k_h2(const float* __restrict__ out1, const float* __restrict__ b1,
                     const float* __restrict__ W2,
                     const float* __restrict__ as2, const float* __restrict__ ad2,
                     float* h2, float* asrc2, float* adst2) {
    __shared__ float sW[128 * 32];
    __shared__ float sx[8][128];
    int tid = threadIdx.x;             // 256
    for (int i = tid; i < 128 * 32; i += 256) sW[i] = W2[i];
    int nl = tid >> 5, j = tid & 31;
    int base = blockIdx.x * 32;
    float es = as2[j], ed = ad2[j];
    for (int it = 0; it < 4; ++it) {
        int n0 = base + it * 8;
        __syncthreads();
        for (int i = tid; i < 1024; i += 256) {
            int r = i >> 7, k = i & 127;
            int n = n0 + r;
            float v = (n < NN) ? out1[(size_t)n * 128 + k] + b1[k] : 0.f;
            sx[r][k] = v > 0.f ? v : expm1f(v);
        }
        __syncthreads();
        int n = n0 + nl;
        float acc = 0.f;
        #pragma unroll 8
        for (int k = 0; k < 128; ++k) acc += sx[nl][k] * sW[k * 32 + j];
        float ps = acc * es, pd = acc * ed;
        #pragma unroll
        for (int m = 16; m >= 1; m >>= 1) { ps += __shfl_xor(ps, m); pd += __shfl_xor(pd, m); }
        if (n < NN) {
            h2[(size_t)n * 32 + j] = acc;
            if (j == 0) { asrc2[n] = ps; adst2[n] = pd; }
        }
    }
}

// ---------------- layer-2 logits + max ----------------
__global__ void k_logit2(const int* __restrict__ ei, const float* __restrict__ eattr,
                         const float* __restrict__ deg, const float* __restrict__ asum,
                         const float* __restrict__ asrc2, const float* __restrict__ adst2,
                         const float* __restrict__ cbuf, float* logit2, float* m2) {
    int e = blockIdx.x * 256 + threadIdx.x;
    if (e >= EP) return;
    int s, d; float a;
    if (e < EE) { s = ei[e]; d = ei[EE + e]; a = eattr[e]; }
    else        { int n = e - EE; s = n; d = n; a = asum[n] / fmaxf(deg[n], 1.f); }
    float z = asrc2[s] + adst2[d] + a * cbuf[4];
    z = z > 0.f ? z : NEG * z;
    logit2[e] = z;
    atomicMaxF(&m2[d], z);
}

__global__ void k_exp2(const int* __restrict__ ei, float* logit2,
                       const float* __restrict__ m2, float* s2) {
    int e = blockIdx.x * 256 + threadIdx.x;
    if (e >= EP) return;
    int d = (e < EE) ? ei[EE + e] : (e - EE);
    float ex = expf(logit2[e] - m2[d]);
    logit2[e] = ex;
    atomicAdd(&s2[d], ex);
}

__global__ void k_norm2(const int* __restrict__ ei, float* logit2, const float* __restrict__ s2) {
    int e = blockIdx.x * 256 + threadIdx.x;
    if (e >= EP) return;
    int d = (e < EE) ? ei[EE + e] : (e - EE);
    logit2[e] /= s2[d];
}

// ---------------- layer-2 scatter aggregate (8 edges / block) ----------------
__global__ void k_agg2(const int* __restrict__ ei, const float* __restrict__ w2,
                       const float* __restrict__ h2, float* dout) {
    int t = blockIdx.x * 256 + threadIdx.x;
    int e = t >> 5;
    int j = t & 31;
    if (e >= EP) return;
    int s, d;
    if (e < EE) { s = ei[e]; d = ei[EE + e]; } else { s = e - EE; d = s; }
    atomicAdd(&dout[(size_t)d * 32 + j], w2[e] * h2[(size_t)s * 32 + j]);
}

extern "C" void kernel_launch(void* const* d_in, const int* in_sizes, int n_in,
                              void* d_out, int out_size, void* d_ws, size_t ws_size,
                              hipStream_t stream) {
    const float* x     = (const float*)d_in[0];
    const int*   ei    = (const int*)d_in[1];
    const float* eattr = (const float*)d_in[2];
    const float* W1    = (const float*)d_in[3];
    const float* as1   = (const float*)d_in[4];
    const float* ad1   = (const float*)d_in[5];
    const float* We1   = (const float*)d_in[6];
    const float* ae1   = (const float*)d_in[7];
    const float* b1    = (const float*)d_in[8];
    const float* W2    = (const float*)d_in[9];
    const float* as2   = (const float*)d_in[10];
    const float* ad2   = (const float*)d_in[11];
    const float* We2   = (const float*)d_in[12];
    const float* ae2   = (const float*)d_in[13];
    const float* b2    = (const float*)d_in[14];
    float* dout = (float*)d_out;

    float* p = (float*)d_ws;
    float* deg    = p; p += NN;
    float* asum   = p; p += NN;
    float* h1     = p; p += (size_t)NN * 128;
    float* asrc1  = p; p += NN * 4;
    float* adst1  = p; p += NN * 4;
    float* logit1 = p; p += (size_t)EP * 4;
    float* m1     = p; p += NN * 4;
    float* s1     = p; p += NN * 4;
    float* out1   = p; p += (size_t)NN * 128;
    float* h2     = p; p += NN * 32;
    float* asrc2  = p; p += NN;
    float* adst2  = p; p += NN;
    float* logit2 = p; p += EP;
    float* m2     = p; p += NN;
    float* s2     = p; p += NN;
    float* cbuf   = p; p += 8;

    k_init  <<<25000, 256, 0, stream>>>(deg, asum, m1, s1, out1, b1, m2, s2, dout, b2);
    k_const <<<1, 128, 0, stream>>>(We1, ae1, We2, ae2, cbuf);
    k_deg   <<<(EE + 255) / 256, 256, 0, stream>>>(ei, eattr, deg, asum);
    k_h1    <<<(NN + 15) / 16, 128, 0, stream>>>(x, W1, as1, ad1, h1, asrc1, adst1);
    k_logit1<<<(EP + 255) / 256, 256, 0, stream>>>(ei, eattr, deg, asum, asrc1, adst1, cbuf, logit1, m1);
    k_exp1  <<<(EP + 255) / 256, 256, 0, stream>>>(ei, logit1, m1, s1);
    k_norm1 <<<(EP + 255) / 256, 256, 0, stream>>>(ei, logit1, s1);
    k_agg1  <<<(EP + 1) / 2, 256, 0, stream>>>(ei, logit1, h1, out1);
    k_h2    <<<(NN + 31) / 32, 256, 0, stream>>>(out1, b1, W2, as2, ad2, h2, asrc2, adst2);
    k_logit2<<<(EP + 255) / 256, 256, 0, stream>>>(ei, eattr, deg, asum, asrc2, adst2, cbuf, logit2, m2);
    k_exp2  <<<(EP + 255) / 256, 256, 0, stream>>>(ei, logit2, m2, s2);
    k_norm2 <<<(EP + 255) / 256, 256, 0, stream>>>(ei, logit2, s2);
    k_agg2  <<<(EP + 7) / 8, 256, 0, stream>>>(ei, logit2, h2, dout);
}

// Round 2
// 689.121 us; speedup vs baseline: 1.6288x; 1.6288x over previous
//
#include <hip/hip_runtime.h>
#include <hip/hip_bf16.h>
#include <math.h>

#define NN 50000
#define EE 800000
#define EP 850000   /* EE + NN self loops */
#define NEG 0.2f

// ---------------- zero degree/attr-sum accumulators ----------------
__global__ void k_zero(int* degi, float* asum) {
    int i = blockIdx.x * 256 + threadIdx.x;
    if (i < NN) { degi[i] = 0; asum[i] = 0.f; }
}

// ---------------- edge-scalar constants ce1[4], ce2 ----------------
__global__ void k_const(const float* __restrict__ We1, const float* __restrict__ ae1,
                        const float* __restrict__ We2, const float* __restrict__ ae2,
                        float* cbuf) {
    int j = threadIdx.x;               // 128 threads
    float p = We1[j] * ae1[j];
    #pragma unroll
    for (int m = 16; m >= 1; m >>= 1) p += __shfl_xor(p, m);
    if ((j & 31) == 0) cbuf[j >> 5] = p;
    if (j < 32) {
        float q = We2[j] * ae2[j];
        #pragma unroll
        for (int m = 16; m >= 1; m >>= 1) q += __shfl_xor(q, m);
        if (j == 0) cbuf[4] = q;
    }
}

// ---------------- int degree + incoming edge_attr sum ----------------
__global__ void k_degi(const int* __restrict__ ei, const float* __restrict__ eattr,
                       int* degi, float* asum) {
    int e = blockIdx.x * 256 + threadIdx.x;
    if (e >= EE) return;
    int d = ei[EE + e];
    atomicAdd(&degi[d], 1);
    atomicAdd(&asum[d], eattr[e]);
}

// ---------------- single-block scan: rowptr, seed self-loops, cursors ----------------
__global__ void k_scan(const int* __restrict__ degi, const float* __restrict__ asum,
                       int* rowptr, int* cursor, int* bsrc, float* battr) {
    __shared__ int part[1024];
    int t = threadIdx.x;
    const int CH = 49;                  // 1024*49 = 50176 >= NN
    int lo = t * CH, hi = min(lo + CH, NN);
    if (lo > NN) hi = lo;
    int s = 0;
    for (int i = lo; i < hi; ++i) s += degi[i] + 1;
    part[t] = s;
    __syncthreads();
    for (int d = 1; d < 1024; d <<= 1) {
        int v = (t >= d) ? part[t - d] : 0;
        __syncthreads();
        part[t] += v;
        __syncthreads();
    }
    int off = part[t] - s;              // exclusive prefix
    for (int i = lo; i < hi; ++i) {
        rowptr[i] = off;
        int dg = degi[i];
        float la = asum[i] / fmaxf((float)dg, 1.f);   // PyG fill_value='mean'
        bsrc[off] = i;                  // self-loop goes first in each segment
        battr[off] = la;
        cursor[i] = off + 1;
        off += dg + 1;
    }
    if (t == 1023) rowptr[NN] = off;    // == EP
}

// ---------------- scatter real edges into CSR buckets ----------------
__global__ void k_scatter(const int* __restrict__ ei, const float* __restrict__ eattr,
                          int* cursor, int* bsrc, float* battr) {
    int e = blockIdx.x * 256 + threadIdx.x;
    if (e >= EE) return;
    int d = ei[EE + e];
    int p = atomicAdd(&cursor[d], 1);
    bsrc[p] = ei[e];
    battr[p] = eattr[e];
}

// ---------------- h1 = x @ W1  [N,128]; per-head att dots ----------------
__global__ void k_h1(const float* __restrict__ x, const float* __restrict__ W1,
                     const float* __restrict__ as1, const float* __restrict__ ad1,
                     float* h1, float* asrc1, float* adst1) {
    __shared__ float sx[4][128];
    int j = threadIdx.x;               // 128 threads, j = output column
    int base = blockIdx.x * 16;
    int h = j >> 5;
    float es = as1[j];
    float ed = ad1[j];
    for (int it = 0; it < 4; ++it) {
        int n0 = base + it * 4;
        __syncthreads();
        #pragma unroll
        for (int r = 0; r < 4; ++r) {
            int n = n0 + r;
            sx[r][j] = (n < NN) ? x[(size_t)n * 128 + j] : 0.f;
        }
        __syncthreads();
        float a0 = 0.f, a1 = 0.f, a2 = 0.f, a3 = 0.f;
        #pragma unroll 8
        for (int k = 0; k < 128; ++k) {
            float w = W1[k * 128 + j];
            a0 += sx[0][k] * w; a1 += sx[1][k] * w;
            a2 += sx[2][k] * w; a3 += sx[3][k] * w;
        }
        float accs[4] = {a0, a1, a2, a3};
        #pragma unroll
        for (int r = 0; r < 4; ++r) {
            int n = n0 + r;
            float v = accs[r];
            float ps = v * es, pd = v * ed;
            #pragma unroll
            for (int m = 16; m >= 1; m >>= 1) { ps += __shfl_xor(ps, m); pd += __shfl_xor(pd, m); }
            if (n < NN) {
                h1[(size_t)n * 128 + j] = v;
                if ((j & 31) == 0) { asrc1[n * 4 + h] = ps; adst1[n * 4 + h] = pd; }
            }
        }
    }
}

// ---------------- layer-1 fused softmax+aggregate: one wave per node ----------------
__global__ void k_gat1(const int* __restrict__ rowptr, const int* __restrict__ bsrc,
                       const float* __restrict__ battr,
                       const float* __restrict__ asrc1, const float* __restrict__ adst1,
                       const float* __restrict__ cbuf, const float* __restrict__ h1,
                       float* out1) {
    int wid = (blockIdx.x * 256 + threadIdx.x) >> 6;   // one wave per node
    if (wid >= NN) return;
    int lane = threadIdx.x & 63;
    int j0 = lane * 2;                  // channels j0, j0+1, same head
    int h = lane >> 4;
    float ce = cbuf[h];
    float ad = adst1[wid * 4 + h];
    int p0 = rowptr[wid], p1 = rowptr[wid + 1];
    float m = -INFINITY, s = 0.f, acc0 = 0.f, acc1 = 0.f;
    for (int p = p0; p < p1; ++p) {
        int src = bsrc[p];
        float a = battr[p];
        float z = asrc1[src * 4 + h] + ad + a * ce;
        z = z > 0.f ? z : NEG * z;
        float2 hv = *(const float2*)&h1[(size_t)src * 128 + j0];
        float mn = fmaxf(m, z);
        float r = expf(m - mn);         // exp(-inf)=0 on first edge
        float w = expf(z - mn);
        s = s * r + w;
        acc0 = acc0 * r + w * hv.x;
        acc1 = acc1 * r + w * hv.y;
        m = mn;
    }
    float inv = 1.f / s;
    float2 o; o.x = acc0 * inv; o.y = acc1 * inv;
    *(float2*)&out1[(size_t)wid * 128 + j0] = o;
}

// ---------------- h2 = elu(out1 + b1) @ W2  [N,32]; layer-2 att dots ----------------
__global__ void k_h2(const float* __restrict__ out1, const float* __restrict__ b1,
                     const float* __restrict__ W2,
                     const float* __restrict__ as2, const float* __restrict__ ad2,
                     float* h2, float* asrc2, float* adst2) {
    __shared__ float sW[128 * 32];
    __shared__ float sx[8][128];
    int tid = threadIdx.x;             // 256
    for (int i = tid; i < 128 * 32; i += 256) sW[i] = W2[i];
    int nl = tid >> 5, j = tid & 31;
    int base = blockIdx.x * 32;
    float es = as2[j], ed = ad2[j];
    for (int it = 0; it < 4; ++it) {
        int n0 = base + it * 8;
        __syncthreads();
        for (int i = tid; i < 1024; i += 256) {
            int r = i >> 7, k = i & 127;
            int n = n0 + r;
            float v = (n < NN) ? out1[(size_t)n * 128 + k] + b1[k] : 0.f;
            sx[r][k] = v > 0.f ? v : expm1f(v);
        }
        __syncthreads();
        int n = n0 + nl;
        float acc = 0.f;
        #pragma unroll 8
        for (int k = 0; k < 128; ++k) acc += sx[nl][k] * sW[k * 32 + j];
        float ps = acc * es, pd = acc * ed;
        #pragma unroll
        for (int m = 16; m >= 1; m >>= 1) { ps += __shfl_xor(ps, m); pd += __shfl_xor(pd, m); }
        if (n < NN) {
            h2[(size_t)n * 32 + j] = acc;
            if (j == 0) { asrc2[n] = ps; adst2[n] = pd; }
        }
    }
}

// ---------------- layer-2 fused softmax+aggregate: half-wave per node ----------------
__global__ void k_gat2(const int* __restrict__ rowptr, const int* __restrict__ bsrc,
                       const float* __restrict__ battr,
                       const float* __restrict__ asrc2, const float* __restrict__ adst2,
                       const float* __restrict__ cbuf, const float* __restrict__ h2,
                       const float* __restrict__ b2, float* dout) {
    int t = blockIdx.x * 256 + threadIdx.x;
    int n = t >> 5;                     // 32 lanes per node
    if (n >= NN) return;
    int j = t & 31;
    float ce = cbuf[4];
    float ad = adst2[n];
    int p0 = rowptr[n], p1 = rowptr[n + 1];
    float m = -INFINITY, s = 0.f, acc = 0.f;
    for (int p = p0; p < p1; ++p) {
        int src = bsrc[p];
        float a = battr[p];
        float z = asrc2[src] + ad + a * ce;
        z = z > 0.f ? z : NEG * z;
        float hv = h2[(size_t)src * 32 + j];
        float mn = fmaxf(m, z);
        float r = expf(m - mn);
        float w = expf(z - mn);
        s = s * r + w;
        acc = acc * r + w * hv;
        m = mn;
    }
    dout[(size_t)n * 32 + j] = acc / s + b2[j];
}

extern "C" void kernel_launch(void* const* d_in, const int* in_sizes, int n_in,
                              void* d_out, int out_size, void* d_ws, size_t ws_size,
                              hipStream_t stream) {
    const float* x     = (const float*)d_in[0];
    const int*   ei    = (const int*)d_in[1];
    const float* eattr = (const float*)d_in[2];
    const float* W1    = (const float*)d_in[3];
    const float* as1   = (const float*)d_in[4];
    const float* ad1   = (const float*)d_in[5];
    const float* We1   = (const float*)d_in[6];
    const float* ae1   = (const float*)d_in[7];
    const float* b1    = (const float*)d_in[8];
    const float* W2    = (const float*)d_in[9];
    const float* as2   = (const float*)d_in[10];
    const float* ad2   = (const float*)d_in[11];
    const float* We2   = (const float*)d_in[12];
    const float* ae2   = (const float*)d_in[13];
    const float* b2    = (const float*)d_in[14];
    float* dout = (float*)d_out;

    char* p = (char*)d_ws;
    int*   degi   = (int*)p;   p += sizeof(int) * NN;
    float* asum   = (float*)p; p += sizeof(float) * NN;
    int*   rowptr = (int*)p;   p += sizeof(int) * (NN + 1);
    int*   cursor = (int*)p;   p += sizeof(int) * NN;
    int*   bsrc   = (int*)p;   p += sizeof(int) * EP;
    float* battr  = (float*)p; p += sizeof(float) * EP;
    float* h1     = (float*)p; p += sizeof(float) * (size_t)NN * 128;
    float* asrc1  = (float*)p; p += sizeof(float) * NN * 4;
    float* adst1  = (float*)p; p += sizeof(float) * NN * 4;
    float* out1   = (float*)p; p += sizeof(float) * (size_t)NN * 128;
    float* h2     = (float*)p; p += sizeof(float) * NN * 32;
    float* asrc2  = (float*)p; p += sizeof(float) * NN;
    float* adst2  = (float*)p; p += sizeof(float) * NN;
    float* cbuf   = (float*)p; p += sizeof(float) * 8;

    k_zero   <<<(NN + 255) / 256, 256, 0, stream>>>(degi, asum);
    k_const  <<<1, 128, 0, stream>>>(We1, ae1, We2, ae2, cbuf);
    k_degi   <<<(EE + 255) / 256, 256, 0, stream>>>(ei, eattr, degi, asum);
    k_scan   <<<1, 1024, 0, stream>>>(degi, asum, rowptr, cursor, bsrc, battr);
    k_scatter<<<(EE + 255) / 256, 256, 0, stream>>>(ei, eattr, cursor, bsrc, battr);
    k_h1     <<<(NN + 15) / 16, 128, 0, stream>>>(x, W1, as1, ad1, h1, asrc1, adst1);
    k_gat1   <<<(NN * 64 + 255) / 256, 256, 0, stream>>>(rowptr, bsrc, battr, asrc1, adst1, cbuf, h1, out1);
    k_h2     <<<(NN + 31) / 32, 256, 0, stream>>>(out1, b1, W2, as2, ad2, h2, asrc2, adst2);
    k_gat2   <<<(NN * 32 + 255) / 256, 256, 0, stream>>>(rowptr, bsrc, battr, asrc2, adst2, cbuf, h2, b2, dout);
}

// Round 6
// 476.190 us; speedup vs baseline: 2.3571x; 1.4472x over previous
//
#include <hip/hip_runtime.h>
#include <hip/hip_bf16.h>
#include <math.h>

#define NN 50000
#define EE 800000
#define EP 850000   /* EE + NN self loops */
#define NB 196      /* (NN+255)/256 scan blocks */
#define NEG 0.2f

// ---------------- zero degree/attr-sum accumulators ----------------
__global__ void k_zero(int* degi, float* asum) {
    int i = blockIdx.x * 256 + threadIdx.x;
    if (i < NN) { degi[i] = 0; asum[i] = 0.f; }
}

// ---------------- edge-scalar constants ce1[4], ce2 ----------------
__global__ void k_const(const float* __restrict__ We1, const float* __restrict__ ae1,
                        const float* __restrict__ We2, const float* __restrict__ ae2,
                        float* cbuf) {
    int j = threadIdx.x;               // 128 threads
    float p = We1[j] * ae1[j];
    #pragma unroll
    for (int m = 16; m >= 1; m >>= 1) p += __shfl_xor(p, m);
    if ((j & 31) == 0) cbuf[j >> 5] = p;
    if (j < 32) {
        float q = We2[j] * ae2[j];
        #pragma unroll
        for (int m = 16; m >= 1; m >>= 1) q += __shfl_xor(q, m);
        if (j == 0) cbuf[4] = q;
    }
}

// ---------------- int degree + incoming edge_attr sum ----------------
__global__ void k_degi(const int* __restrict__ ei, const float* __restrict__ eattr,
                       int* degi, float* asum) {
    int e = blockIdx.x * 256 + threadIdx.x;
    if (e >= EE) return;
    int d = ei[EE + e];
    atomicAdd(&degi[d], 1);
    atomicAdd(&asum[d], eattr[e]);
}

// ---------------- hierarchical scan over deg+1 ----------------
__global__ void k_scan1(const int* __restrict__ degi, int* rowptr, int* blksum) {
    __shared__ int part[256];
    int t = threadIdx.x;
    int i = blockIdx.x * 256 + t;
    int v = (i < NN) ? degi[i] + 1 : 0;
    part[t] = v;
    __syncthreads();
    #pragma unroll
    for (int d = 1; d < 256; d <<= 1) {
        int u = (t >= d) ? part[t - d] : 0;
        __syncthreads();
        part[t] += u;
        __syncthreads();
    }
    if (i < NN) rowptr[i] = part[t] - v;          // local exclusive prefix
    if (t == 255) blksum[blockIdx.x] = part[255]; // block total
}

__global__ void k_scan2(int* blksum) {
    __shared__ int part[256];
    int t = threadIdx.x;
    int v = (t < NB) ? blksum[t] : 0;
    part[t] = v;
    __syncthreads();
    #pragma unroll
    for (int d = 1; d < 256; d <<= 1) {
        int u = (t >= d) ? part[t - d] : 0;
        __syncthreads();
        part[t] += u;
        __syncthreads();
    }
    if (t < NB) blksum[t] = part[t] - v;          // exclusive block offsets
}

__global__ void k_scan3(const int* __restrict__ degi, const float* __restrict__ asum,
                        int* rowptr, const int* __restrict__ blksum,
                        int* cursor, int* bsrc, float* battr) {
    int i = blockIdx.x * 256 + threadIdx.x;
    if (i >= NN) return;
    int off = rowptr[i] + blksum[blockIdx.x];
    rowptr[i] = off;
    int dg = degi[i];
    bsrc[off] = i;                                 // self-loop first in segment
    battr[off] = asum[i] / fmaxf((float)dg, 1.f);  // PyG fill_value='mean'
    cursor[i] = off + 1;
    if (i == 0) rowptr[NN] = EP;
}

// ---------------- scatter real edges into CSR buckets ----------------
__global__ void k_scatter(const int* __restrict__ ei, const float* __restrict__ eattr,
                          int* cursor, int* bsrc, float* battr) {
    int e = blockIdx.x * 256 + threadIdx.x;
    if (e >= EE) return;
    int d = ei[EE + e];
    int p = atomicAdd(&cursor[d], 1);
    bsrc[p] = ei[e];
    battr[p] = eattr[e];
}

// ---------------- h1 = x @ W1  [N,128]; per-head att dots ----------------
__global__ void k_h1(const float* __restrict__ x, const float* __restrict__ W1,
                     const float* __restrict__ as1, const float* __restrict__ ad1,
                     float* h1, float* asrc1, float* adst1) {
    __shared__ float sx[4][128];
    int j = threadIdx.x;               // 128 threads, j = output column
    int base = blockIdx.x * 16;
    int h = j >> 5;
    float es = as1[j];
    float ed = ad1[j];
    for (int it = 0; it < 4; ++it) {
        int n0 = base + it * 4;
        __syncthreads();
        #pragma unroll
        for (int r = 0; r < 4; ++r) {
            int n = n0 + r;
            sx[r][j] = (n < NN) ? x[(size_t)n * 128 + j] : 0.f;
        }
        __syncthreads();
        float a0 = 0.f, a1 = 0.f, a2 = 0.f, a3 = 0.f;
        #pragma unroll 8
        for (int k = 0; k < 128; ++k) {
            float w = W1[k * 128 + j];
            a0 += sx[0][k] * w; a1 += sx[1][k] * w;
            a2 += sx[2][k] * w; a3 += sx[3][k] * w;
        }
        float accs[4] = {a0, a1, a2, a3};
        #pragma unroll
        for (int r = 0; r < 4; ++r) {
            int n = n0 + r;
            float v = accs[r];
            float ps = v * es, pd = v * ed;
            #pragma unroll
            for (int m = 16; m >= 1; m >>= 1) { ps += __shfl_xor(ps, m); pd += __shfl_xor(pd, m); }
            if (n < NN) {
                h1[(size_t)n * 128 + j] = v;
                if ((j & 31) == 0) { asrc1[n * 4 + h] = ps; adst1[n * 4 + h] = pd; }
            }
        }
    }
}

// ---------------- layer-1 fused softmax+aggregate: one wave per node ----------------
__global__ void k_gat1(const int* __restrict__ rowptr, const int* __restrict__ bsrc,
                       const float* __restrict__ battr,
                       const float* __restrict__ asrc1, const float* __restrict__ adst1,
                       const float* __restrict__ cbuf, const float* __restrict__ h1,
                       float* out1) {
    int wid = (blockIdx.x * 256 + threadIdx.x) >> 6;   // one wave per node
    if (wid >= NN) return;
    int lane = threadIdx.x & 63;
    int j0 = lane * 2;                  // channels j0, j0+1, same head
    int h = lane >> 4;
    float ce = cbuf[h];
    float ad = adst1[wid * 4 + h];
    int p0 = rowptr[wid], p1 = rowptr[wid + 1];
    float m = -INFINITY, s = 0.f, acc0 = 0.f, acc1 = 0.f;
    for (int p = p0; p < p1; ++p) {
        int src = bsrc[p];
        float a = battr[p];
        float z = asrc1[src * 4 + h] + ad + a * ce;
        z = z > 0.f ? z : NEG * z;
        float2 hv = *(const float2*)&h1[(size_t)src * 128 + j0];
        float mn = fmaxf(m, z);
        float r = expf(m - mn);         // exp(-inf)=0 on first edge
        float w = expf(z - mn);
        s = s * r + w;
        acc0 = acc0 * r + w * hv.x;
        acc1 = acc1 * r + w * hv.y;
        m = mn;
    }
    float inv = 1.f / s;
    float2 o; o.x = acc0 * inv; o.y = acc1 * inv;
    *(float2*)&out1[(size_t)wid * 128 + j0] = o;
}

// ---------------- h2 = elu(out1 + b1) @ W2  [N,32]; layer-2 att dots ----------------
__global__ void k_h2(const float* __restrict__ out1, const float* __restrict__ b1,
                     const float* __restrict__ W2,
                     const float* __restrict__ as2, const float* __restrict__ ad2,
                     float* h2, float* asrc2, float* adst2) {
    __shared__ float sW[128 * 32];
    __shared__ float sx[8][128];
    int tid = threadIdx.x;             // 256
    for (int i = tid; i < 128 * 32; i += 256) sW[i] = W2[i];
    int nl = tid >> 5, j = tid & 31;
    int base = blockIdx.x * 32;
    float es = as2[j], ed = ad2[j];
    for (int it = 0; it < 4; ++it) {
        int n0 = base + it * 8;
        __syncthreads();
        for (int i = tid; i < 1024; i += 256) {
            int r = i >> 7, k = i & 127;
            int n = n0 + r;
            float v = (n < NN) ? out1[(size_t)n * 128 + k] + b1[k] : 0.f;
            sx[r][k] = v > 0.f ? v : expm1f(v);
        }
        __syncthreads();
        int n = n0 + nl;
        float acc = 0.f;
        #pragma unroll 8
        for (int k = 0; k < 128; ++k) acc += sx[nl][k] * sW[k * 32 + j];
        float ps = acc * es, pd = acc * ed;
        #pragma unroll
        for (int m = 16; m >= 1; m >>= 1) { ps += __shfl_xor(ps, m); pd += __shfl_xor(pd, m); }
        if (n < NN) {
            h2[(size_t)n * 32 + j] = acc;
            if (j == 0) { asrc2[n] = ps; adst2[n] = pd; }
        }
    }
}

// ---------------- layer-2 fused softmax+aggregate: half-wave per node ----------------
__global__ void k_gat2(const int* __restrict__ rowptr, const int* __restrict__ bsrc,
                       const float* __restrict__ battr,
                       const float* __restrict__ asrc2, const float* __restrict__ adst2,
                       const float* __restrict__ cbuf, const float* __restrict__ h2,
                       const float* __restrict__ b2, float* dout) {
    int t = blockIdx.x * 256 + threadIdx.x;
    int n = t >> 5;                     // 32 lanes per node
    if (n >= NN) return;
    int j = t & 31;
    float ce = cbuf[4];
    float ad = adst2[n];
    int p0 = rowptr[n], p1 = rowptr[n + 1];
    float m = -INFINITY, s = 0.f, acc = 0.f;
    for (int p = p0; p < p1; ++p) {
        int src = bsrc[p];
        float a = battr[p];
        float z = asrc2[src] + ad + a * ce;
        z = z > 0.f ? z : NEG * z;
        float hv = h2[(size_t)src * 32 + j];
        float mn = fmaxf(m, z);
        float r = expf(m - mn);
        float w = expf(z - mn);
        s = s * r + w;
        acc = acc * r + w * hv;
        m = mn;
    }
    dout[(size_t)n * 32 + j] = acc / s + b2[j];
}

extern "C" void kernel_launch(void* const* d_in, const int* in_sizes, int n_in,
                              void* d_out, int out_size, void* d_ws, size_t ws_size,
                              hipStream_t stream) {
    const float* x     = (const float*)d_in[0];
    const int*   ei    = (const int*)d_in[1];
    const float* eattr = (const float*)d_in[2];
    const float* W1    = (const float*)d_in[3];
    const float* as1   = (const float*)d_in[4];
    const float* ad1   = (const float*)d_in[5];
    const float* We1   = (const float*)d_in[6];
    const float* ae1   = (const float*)d_in[7];
    const float* b1    = (const float*)d_in[8];
    const float* W2    = (const float*)d_in[9];
    const float* as2   = (const float*)d_in[10];
    const float* ad2   = (const float*)d_in[11];
    const float* We2   = (const float*)d_in[12];
    const float* ae2   = (const float*)d_in[13];
    const float* b2    = (const float*)d_in[14];
    float* dout = (float*)d_out;

    char* p = (char*)d_ws;
    int*   degi   = (int*)p;   p += sizeof(int) * NN;
    float* asum   = (float*)p; p += sizeof(float) * NN;
    int*   rowptr = (int*)p;   p += sizeof(int) * (NN + 1);
    int*   cursor = (int*)p;   p += sizeof(int) * NN;
    int*   blksum = (int*)p;   p += sizeof(int) * 256;
    int*   bsrc   = (int*)p;   p += sizeof(int) * EP;
    float* battr  = (float*)p; p += sizeof(float) * EP;
    float* h1     = (float*)p; p += sizeof(float) * (size_t)NN * 128;
    float* asrc1  = (float*)p; p += sizeof(float) * NN * 4;
    float* adst1  = (float*)p; p += sizeof(float) * NN * 4;
    float* out1   = (float*)p; p += sizeof(float) * (size_t)NN * 128;
    float* h2     = (float*)p; p += sizeof(float) * NN * 32;
    float* asrc2  = (float*)p; p += sizeof(float) * NN;
    float* adst2  = (float*)p; p += sizeof(float) * NN;
    float* cbuf   = (float*)p; p += sizeof(float) * 8;

    k_zero   <<<(NN + 255) / 256, 256, 0, stream>>>(degi, asum);
    k_const  <<<1, 128, 0, stream>>>(We1, ae1, We2, ae2, cbuf);
    k_degi   <<<(EE + 255) / 256, 256, 0, stream>>>(ei, eattr, degi, asum);
    k_scan1  <<<NB, 256, 0, stream>>>(degi, rowptr, blksum);
    k_scan2  <<<1, 256, 0, stream>>>(blksum);
    k_scan3  <<<NB, 256, 0, stream>>>(degi, asum, rowptr, blksum, cursor, bsrc, battr);
    k_scatter<<<(EE + 255) / 256, 256, 0, stream>>>(ei, eattr, cursor, bsrc, battr);
    k_h1     <<<(NN + 15) / 16, 128, 0, stream>>>(x, W1, as1, ad1, h1, asrc1, adst1);
    k_gat1   <<<(NN * 64 + 255) / 256, 256, 0, stream>>>(rowptr, bsrc, battr, asrc1, adst1, cbuf, h1, out1);
    k_h2     <<<(NN + 31) / 32, 256, 0, stream>>>(out1, b1, W2, as2, ad2, h2, asrc2, adst2);
    k_gat2   <<<(NN * 32 + 255) / 256, 256, 0, stream>>>(rowptr, bsrc, battr, asrc2, adst2, cbuf, h2, b2, dout);
}

// Round 7
// 461.911 us; speedup vs baseline: 2.4299x; 1.0309x over previous
//
#include <hip/hip_runtime.h>
#include <hip/hip_bf16.h>
#include <math.h>

#define NN 50000
#define EE 800000
#define EP 850000   /* EE + NN self loops */
#define NB 196      /* (NN+255)/256 scan blocks */
#define NEG 0.2f
#define LOG2E 1.4426950408889634f

// ---------------- zero degree/attr-sum accumulators ----------------
__global__ void k_zero(int* degi, float* asum) {
    int i = blockIdx.x * 256 + threadIdx.x;
    if (i < NN) { degi[i] = 0; asum[i] = 0.f; }
}

// ---------------- edge-scalar constants ce1[4], ce2 ----------------
__global__ void k_const(const float* __restrict__ We1, const float* __restrict__ ae1,
                        const float* __restrict__ We2, const float* __restrict__ ae2,
                        float* cbuf) {
    int j = threadIdx.x;               // 128 threads
    float p = We1[j] * ae1[j];
    #pragma unroll
    for (int m = 16; m >= 1; m >>= 1) p += __shfl_xor(p, m);
    if ((j & 31) == 0) cbuf[j >> 5] = p;
    if (j < 32) {
        float q = We2[j] * ae2[j];
        #pragma unroll
        for (int m = 16; m >= 1; m >>= 1) q += __shfl_xor(q, m);
        if (j == 0) cbuf[4] = q;
    }
}

// ---------------- int degree + incoming edge_attr sum ----------------
__global__ void k_degi(const int* __restrict__ ei, const float* __restrict__ eattr,
                       int* degi, float* asum) {
    int e = blockIdx.x * 256 + threadIdx.x;
    if (e >= EE) return;
    int d = ei[EE + e];
    atomicAdd(&degi[d], 1);
    atomicAdd(&asum[d], eattr[e]);
}

// ---------------- hierarchical scan over deg+1 ----------------
__global__ void k_scan1(const int* __restrict__ degi, int* rowptr, int* blksum) {
    __shared__ int part[256];
    int t = threadIdx.x;
    int i = blockIdx.x * 256 + t;
    int v = (i < NN) ? degi[i] + 1 : 0;
    part[t] = v;
    __syncthreads();
    #pragma unroll
    for (int d = 1; d < 256; d <<= 1) {
        int u = (t >= d) ? part[t - d] : 0;
        __syncthreads();
        part[t] += u;
        __syncthreads();
    }
    if (i < NN) rowptr[i] = part[t] - v;          // local exclusive prefix
    if (t == 255) blksum[blockIdx.x] = part[255]; // block total
}

__global__ void k_scan2(int* blksum) {
    __shared__ int part[256];
    int t = threadIdx.x;
    int v = (t < NB) ? blksum[t] : 0;
    part[t] = v;
    __syncthreads();
    #pragma unroll
    for (int d = 1; d < 256; d <<= 1) {
        int u = (t >= d) ? part[t - d] : 0;
        __syncthreads();
        part[t] += u;
        __syncthreads();
    }
    if (t < NB) blksum[t] = part[t] - v;          // exclusive block offsets
}

__global__ void k_scan3(const int* __restrict__ degi, const float* __restrict__ asum,
                        int* rowptr, const int* __restrict__ blksum,
                        int* cursor, int* bsrc, int* bdst, float* battr) {
    int i = blockIdx.x * 256 + threadIdx.x;
    if (i >= NN) return;
    int off = rowptr[i] + blksum[blockIdx.x];
    rowptr[i] = off;
    int dg = degi[i];
    bsrc[off] = i;                                 // self-loop first in segment
    bdst[off] = i;
    battr[off] = asum[i] / fmaxf((float)dg, 1.f);  // PyG fill_value='mean'
    cursor[i] = off + 1;
    if (i == 0) rowptr[NN] = EP;
}

// ---------------- scatter real edges into CSR buckets ----------------
__global__ void k_scatter(const int* __restrict__ ei, const float* __restrict__ eattr,
                          int* cursor, int* bsrc, int* bdst, float* battr) {
    int e = blockIdx.x * 256 + threadIdx.x;
    if (e >= EE) return;
    int d = ei[EE + e];
    int p = atomicAdd(&cursor[d], 1);
    bsrc[p] = ei[e];
    bdst[p] = d;
    battr[p] = eattr[e];
}

// ---------------- h1 = x @ W1  [N,128]; per-head att dots ----------------
__global__ void k_h1(const float* __restrict__ x, const float* __restrict__ W1,
                     const float* __restrict__ as1, const float* __restrict__ ad1,
                     float* h1, float* asrc1, float* adst1) {
    __shared__ float sx[4][128];
    int j = threadIdx.x;               // 128 threads, j = output column
    int base = blockIdx.x * 16;
    int h = j >> 5;
    float es = as1[j];
    float ed = ad1[j];
    for (int it = 0; it < 4; ++it) {
        int n0 = base + it * 4;
        __syncthreads();
        #pragma unroll
        for (int r = 0; r < 4; ++r) {
            int n = n0 + r;
            sx[r][j] = (n < NN) ? x[(size_t)n * 128 + j] : 0.f;
        }
        __syncthreads();
        float a0 = 0.f, a1 = 0.f, a2 = 0.f, a3 = 0.f;
        #pragma unroll 8
        for (int k = 0; k < 128; ++k) {
            float w = W1[k * 128 + j];
            a0 += sx[0][k] * w; a1 += sx[1][k] * w;
            a2 += sx[2][k] * w; a3 += sx[3][k] * w;
        }
        float accs[4] = {a0, a1, a2, a3};
        #pragma unroll
        for (int r = 0; r < 4; ++r) {
            int n = n0 + r;
            float v = accs[r];
            float ps = v * es, pd = v * ed;
            #pragma unroll
            for (int m = 16; m >= 1; m >>= 1) { ps += __shfl_xor(ps, m); pd += __shfl_xor(pd, m); }
            if (n < NN) {
                h1[(size_t)n * 128 + j] = v;
                if ((j & 31) == 0) { asrc1[n * 4 + h] = ps; adst1[n * 4 + h] = pd; }
            }
        }
    }
}

// ---------------- layer-1 logits, edge-parallel, log2e-scaled ----------------
__global__ void k_z1(const int* __restrict__ bsrc, const int* __restrict__ bdst,
                     const float* __restrict__ battr,
                     const float* __restrict__ asrc1, const float* __restrict__ adst1,
                     const float* __restrict__ cbuf, float* z1) {
    int p = blockIdx.x * 256 + threadIdx.x;
    if (p >= EP) return;
    int s = bsrc[p], d = bdst[p];
    float a = battr[p];
    const float4 vs = *(const float4*)&asrc1[s * 4];
    const float4 vd = *(const float4*)&adst1[d * 4];
    float4 z;
    z.x = vs.x + vd.x + a * cbuf[0];
    z.y = vs.y + vd.y + a * cbuf[1];
    z.z = vs.z + vd.z + a * cbuf[2];
    z.w = vs.w + vd.w + a * cbuf[3];
    z.x = (z.x > 0.f ? z.x : NEG * z.x) * LOG2E;
    z.y = (z.y > 0.f ? z.y : NEG * z.y) * LOG2E;
    z.z = (z.z > 0.f ? z.z : NEG * z.z) * LOG2E;
    z.w = (z.w > 0.f ? z.w : NEG * z.w) * LOG2E;
    *(float4*)&z1[(size_t)p * 4] = z;
}

// ---------------- layer-1 two-pass softmax+aggregate: one wave per node ----------------
__global__ void k_gat1(const int* __restrict__ rowptr, const int* __restrict__ bsrc,
                       const float* __restrict__ z1, const float* __restrict__ h1,
                       float* out1) {
    int wid = (blockIdx.x * 256 + threadIdx.x) >> 6;   // one wave per node
    if (wid >= NN) return;
    int lane = threadIdx.x & 63;
    int p0 = rowptr[wid], p1 = rowptr[wid + 1];
    // pass A: lane-parallel componentwise max over the node's edges
    float4 m4 = make_float4(-INFINITY, -INFINITY, -INFINITY, -INFINITY);
    for (int p = p0 + lane; p < p1; p += 64) {
        const float4 z = *(const float4*)&z1[(size_t)p * 4];
        m4.x = fmaxf(m4.x, z.x); m4.y = fmaxf(m4.y, z.y);
        m4.z = fmaxf(m4.z, z.z); m4.w = fmaxf(m4.w, z.w);
    }
    #pragma unroll
    for (int k = 32; k >= 1; k >>= 1) {
        m4.x = fmaxf(m4.x, __shfl_xor(m4.x, k));
        m4.y = fmaxf(m4.y, __shfl_xor(m4.y, k));
        m4.z = fmaxf(m4.z, __shfl_xor(m4.z, k));
        m4.w = fmaxf(m4.w, __shfl_xor(m4.w, k));
    }
    int h = lane >> 4;
    float m = (h == 0) ? m4.x : (h == 1) ? m4.y : (h == 2) ? m4.z : m4.w;
    int j0 = lane * 2;
    // pass B: single native exp2 per edge, plain FMA accumulate (no rescale)
    float s = 0.f, acc0 = 0.f, acc1 = 0.f;
    int p = p0;
    for (; p + 2 <= p1; p += 2) {
        float zA = z1[(size_t)p * 4 + h];
        float zB = z1[(size_t)(p + 1) * 4 + h];
        int sA = bsrc[p], sB = bsrc[p + 1];
        float wA = exp2f(zA - m), wB = exp2f(zB - m);
        const float2 hA = *(const float2*)&h1[(size_t)sA * 128 + j0];
        const float2 hB = *(const float2*)&h1[(size_t)sB * 128 + j0];
        s += wA + wB;
        acc0 += wA * hA.x + wB * hB.x;
        acc1 += wA * hA.y + wB * hB.y;
    }
    if (p < p1) {
        float z = z1[(size_t)p * 4 + h];
        int sA = bsrc[p];
        float w = exp2f(z - m);
        const float2 hA = *(const float2*)&h1[(size_t)sA * 128 + j0];
        s += w; acc0 += w * hA.x; acc1 += w * hA.y;
    }
    float inv = 1.f / s;
    float2 o; o.x = acc0 * inv; o.y = acc1 * inv;
    *(float2*)&out1[(size_t)wid * 128 + j0] = o;
}

// ---------------- h2 = elu(out1 + b1) @ W2  [N,32]; layer-2 att dots ----------------
__global__ void k_h2(const float* __restrict__ out1, const float* __restrict__ b1,
                     const float* __restrict__ W2,
                     const float* __restrict__ as2, const float* __restrict__ ad2,
                     float* h2, float* asrc2, float* adst2) {
    __shared__ float sW[128 * 32];
    __shared__ float sx[8][128];
    int tid = threadIdx.x;             // 256
    for (int i = tid; i < 128 * 32; i += 256) sW[i] = W2[i];
    int nl = tid >> 5, j = tid & 31;
    int base = blockIdx.x * 32;
    float es = as2[j], ed = ad2[j];
    for (int it = 0; it < 4; ++it) {
        int n0 = base + it * 8;
        __syncthreads();
        for (int i = tid; i < 1024; i += 256) {
            int r = i >> 7, k = i & 127;
            int n = n0 + r;
            float v = (n < NN) ? out1[(size_t)n * 128 + k] + b1[k] : 0.f;
            sx[r][k] = v > 0.f ? v : expm1f(v);
        }
        __syncthreads();
        int n = n0 + nl;
        float acc = 0.f;
        #pragma unroll 8
        for (int k = 0; k < 128; ++k) acc += sx[nl][k] * sW[k * 32 + j];
        float ps = acc * es, pd = acc * ed;
        #pragma unroll
        for (int m = 16; m >= 1; m >>= 1) { ps += __shfl_xor(ps, m); pd += __shfl_xor(pd, m); }
        if (n < NN) {
            h2[(size_t)n * 32 + j] = acc;
            if (j == 0) { asrc2[n] = ps; adst2[n] = pd; }
        }
    }
}

// ---------------- layer-2 logits, edge-parallel, log2e-scaled ----------------
__global__ void k_z2(const int* __restrict__ bsrc, const int* __restrict__ bdst,
                     const float* __restrict__ battr,
                     const float* __restrict__ asrc2, const float* __restrict__ adst2,
                     const float* __restrict__ cbuf, float* z2) {
    int p = blockIdx.x * 256 + threadIdx.x;
    if (p >= EP) return;
    float z = asrc2[bsrc[p]] + adst2[bdst[p]] + battr[p] * cbuf[4];
    z = z > 0.f ? z : NEG * z;
    z2[p] = z * LOG2E;
}

// ---------------- layer-2 two-pass softmax+aggregate: one wave per node ----------------
__global__ void k_gat2(const int* __restrict__ rowptr, const int* __restrict__ bsrc,
                       const float* __restrict__ z2, const float* __restrict__ h2,
                       const float* __restrict__ b2, float* dout) {
    int wid = (blockIdx.x * 256 + threadIdx.x) >> 6;   // one wave per node
    if (wid >= NN) return;
    int lane = threadIdx.x & 63;
    int j = lane & 31, eo = lane >> 5;
    int p0 = rowptr[wid], p1 = rowptr[wid + 1];
    // pass A: lane-parallel max
    float m = -INFINITY;
    for (int p = p0 + lane; p < p1; p += 64) m = fmaxf(m, z2[p]);
    #pragma unroll
    for (int k = 32; k >= 1; k >>= 1) m = fmaxf(m, __shfl_xor(m, k));
    // pass B: two edges per iteration (halves of the wave), combine at end
    float s = 0.f, acc = 0.f;
    for (int p = p0 + eo; p < p1; p += 2) {
        float w = exp2f(z2[p] - m);
        int src = bsrc[p];
        s += w;
        acc += w * h2[(size_t)src * 32 + j];
    }
    s += __shfl_xor(s, 32);
    acc += __shfl_xor(acc, 32);
    if (eo == 0) dout[(size_t)wid * 32 + j] = acc / s + b2[j];
}

extern "C" void kernel_launch(void* const* d_in, const int* in_sizes, int n_in,
                              void* d_out, int out_size, void* d_ws, size_t ws_size,
                              hipStream_t stream) {
    const float* x     = (const float*)d_in[0];
    const int*   ei    = (const int*)d_in[1];
    const float* eattr = (const float*)d_in[2];
    const float* W1    = (const float*)d_in[3];
    const float* as1   = (const float*)d_in[4];
    const float* ad1   = (const float*)d_in[5];
    const float* We1   = (const float*)d_in[6];
    const float* ae1   = (const float*)d_in[7];
    const float* b1    = (const float*)d_in[8];
    const float* W2    = (const float*)d_in[9];
    const float* as2   = (const float*)d_in[10];
    const float* ad2   = (const float*)d_in[11];
    const float* We2   = (const float*)d_in[12];
    const float* ae2   = (const float*)d_in[13];
    const float* b2    = (const float*)d_in[14];
    float* dout = (float*)d_out;

    char* p = (char*)d_ws;
    int*   degi   = (int*)p;   p += sizeof(int) * NN;
    float* asum   = (float*)p; p += sizeof(float) * NN;
    int*   rowptr = (int*)p;   p += sizeof(int) * (NN + 4);   // padded for 16B alignment
    int*   cursor = (int*)p;   p += sizeof(int) * NN;
    int*   blksum = (int*)p;   p += sizeof(int) * 256;
    int*   bsrc   = (int*)p;   p += sizeof(int) * EP;
    int*   bdst   = (int*)p;   p += sizeof(int) * EP;
    float* battr  = (float*)p; p += sizeof(float) * EP;
    float* z1     = (float*)p; p += sizeof(float) * (size_t)EP * 4;  // 16B-aligned
    float* h1     = (float*)p; p += sizeof(float) * (size_t)NN * 128;
    float* asrc1  = (float*)p; p += sizeof(float) * NN * 4;
    float* adst1  = (float*)p; p += sizeof(float) * NN * 4;
    float* out1   = (float*)p; p += sizeof(float) * (size_t)NN * 128;
    float* h2     = (float*)p; p += sizeof(float) * NN * 32;
    float* asrc2  = (float*)p; p += sizeof(float) * NN;
    float* adst2  = (float*)p; p += sizeof(float) * NN;
    float* cbuf   = (float*)p; p += sizeof(float) * 8;
    float* z2     = z1;   // reuse: z1 dead after k_gat1

    k_zero   <<<(NN + 255) / 256, 256, 0, stream>>>(degi, asum);
    k_const  <<<1, 128, 0, stream>>>(We1, ae1, We2, ae2, cbuf);
    k_degi   <<<(EE + 255) / 256, 256, 0, stream>>>(ei, eattr, degi, asum);
    k_scan1  <<<NB, 256, 0, stream>>>(degi, rowptr, blksum);
    k_scan2  <<<1, 256, 0, stream>>>(blksum);
    k_scan3  <<<NB, 256, 0, stream>>>(degi, asum, rowptr, blksum, cursor, bsrc, bdst, battr);
    k_scatter<<<(EE + 255) / 256, 256, 0, stream>>>(ei, eattr, cursor, bsrc, bdst, battr);
    k_h1     <<<(NN + 15) / 16, 128, 0, stream>>>(x, W1, as1, ad1, h1, asrc1, adst1);
    k_z1     <<<(EP + 255) / 256, 256, 0, stream>>>(bsrc, bdst, battr, asrc1, adst1, cbuf, z1);
    k_gat1   <<<(NN * 64 + 255) / 256, 256, 0, stream>>>(rowptr, bsrc, z1, h1, out1);
    k_h2     <<<(NN + 31) / 32, 256, 0, stream>>>(out1, b1, W2, as2, ad2, h2, asrc2, adst2);
    k_z2     <<<(EP + 255) / 256, 256, 0, stream>>>(bsrc, bdst, battr, asrc2, adst2, cbuf, z2);
    k_gat2   <<<(NN * 64 + 255) / 256, 256, 0, stream>>>(rowptr, bsrc, z2, h2, b2, dout);
}

// Round 11
// 417.099 us; speedup vs baseline: 2.6910x; 1.1074x over previous
//
#include <hip/hip_runtime.h>
#include <hip/hip_bf16.h>
#include <math.h>

#define NN 50000
#define EE 800000
#define EP 850000   /* EE + NN self loops */
#define NB 196      /* (NN+255)/256 scan blocks */
#define NEG 0.2f
#define LOG2E 1.4426950408889634f

// ---------------- zero degree/attr-sum accumulators ----------------
__global__ void k_zero(int* degi, float* asum) {
    int i = blockIdx.x * 256 + threadIdx.x;
    if (i < NN) { degi[i] = 0; asum[i] = 0.f; }
}

// ---------------- edge-scalar constants ce1[4], ce2 ----------------
__global__ void k_const(const float* __restrict__ We1, const float* __restrict__ ae1,
                        const float* __restrict__ We2, const float* __restrict__ ae2,
                        float* cbuf) {
    int j = threadIdx.x;               // 128 threads
    float p = We1[j] * ae1[j];
    #pragma unroll
    for (int m = 16; m >= 1; m >>= 1) p += __shfl_xor(p, m);
    if ((j & 31) == 0) cbuf[j >> 5] = p;
    if (j < 32) {
        float q = We2[j] * ae2[j];
        #pragma unroll
        for (int m = 16; m >= 1; m >>= 1) q += __shfl_xor(q, m);
        if (j == 0) cbuf[4] = q;
    }
}

// ---------------- int degree + incoming edge_attr sum ----------------
__global__ void k_degi(const int* __restrict__ ei, const float* __restrict__ eattr,
                       int* degi, float* asum) {
    int e = blockIdx.x * 256 + threadIdx.x;
    if (e >= EE) return;
    int d = ei[EE + e];
    atomicAdd(&degi[d], 1);
    atomicAdd(&asum[d], eattr[e]);
}

// ---------------- hierarchical scan over deg+1 ----------------
__global__ void k_scan1(const int* __restrict__ degi, int* rowptr, int* blksum) {
    __shared__ int part[256];
    int t = threadIdx.x;
    int i = blockIdx.x * 256 + t;
    int v = (i < NN) ? degi[i] + 1 : 0;
    part[t] = v;
    __syncthreads();
    #pragma unroll
    for (int d = 1; d < 256; d <<= 1) {
        int u = (t >= d) ? part[t - d] : 0;
        __syncthreads();
        part[t] += u;
        __syncthreads();
    }
    if (i < NN) rowptr[i] = part[t] - v;          // local exclusive prefix
    if (t == 255) blksum[blockIdx.x] = part[255]; // block total
}

__global__ void k_scan2(int* blksum) {
    __shared__ int part[256];
    int t = threadIdx.x;
    int v = (t < NB) ? blksum[t] : 0;
    part[t] = v;
    __syncthreads();
    #pragma unroll
    for (int d = 1; d < 256; d <<= 1) {
        int u = (t >= d) ? part[t - d] : 0;
        __syncthreads();
        part[t] += u;
        __syncthreads();
    }
    if (t < NB) blksum[t] = part[t] - v;          // exclusive block offsets
}

__global__ void k_scan3(const int* __restrict__ degi, const float* __restrict__ asum,
                        int* rowptr, const int* __restrict__ blksum,
                        int* cursor, int* bsrc, int* bdst, float* battr) {
    int i = blockIdx.x * 256 + threadIdx.x;
    if (i >= NN) return;
    int off = rowptr[i] + blksum[blockIdx.x];
    rowptr[i] = off;
    int dg = degi[i];
    bsrc[off] = i;                                 // self-loop first in segment
    bdst[off] = i;
    battr[off] = asum[i] / fmaxf((float)dg, 1.f);  // PyG fill_value='mean'
    cursor[i] = off + 1;
    if (i == 0) rowptr[NN] = EP;
}

// ---------------- scatter real edges into CSR buckets ----------------
__global__ void k_scatter(const int* __restrict__ ei, const float* __restrict__ eattr,
                          int* cursor, int* bsrc, int* bdst, float* battr) {
    int e = blockIdx.x * 256 + threadIdx.x;
    if (e >= EE) return;
    int d = ei[EE + e];
    int p = atomicAdd(&cursor[d], 1);
    bsrc[p] = ei[e];
    bdst[p] = d;
    battr[p] = eattr[e];
}

// ---------------- h1 = x @ W1  [N,128] (bf16 store); per-head att dots (fp32) ----------------
__global__ void k_h1(const float* __restrict__ x, const float* __restrict__ W1,
                     const float* __restrict__ as1, const float* __restrict__ ad1,
                     __hip_bfloat16* h1b, float* asrc1, float* adst1) {
    __shared__ float sx[4][128];
    int j = threadIdx.x;               // 128 threads, j = output column
    int base = blockIdx.x * 16;
    int h = j >> 5;
    float es = as1[j];
    float ed = ad1[j];
    for (int it = 0; it < 4; ++it) {
        int n0 = base + it * 4;
        __syncthreads();
        #pragma unroll
        for (int r = 0; r < 4; ++r) {
            int n = n0 + r;
            sx[r][j] = (n < NN) ? x[(size_t)n * 128 + j] : 0.f;
        }
        __syncthreads();
        float a0 = 0.f, a1 = 0.f, a2 = 0.f, a3 = 0.f;
        #pragma unroll 8
        for (int k = 0; k < 128; ++k) {
            float w = W1[k * 128 + j];
            a0 += sx[0][k] * w; a1 += sx[1][k] * w;
            a2 += sx[2][k] * w; a3 += sx[3][k] * w;
        }
        float accs[4] = {a0, a1, a2, a3};
        #pragma unroll
        for (int r = 0; r < 4; ++r) {
            int n = n0 + r;
            float v = accs[r];
            float ps = v * es, pd = v * ed;
            #pragma unroll
            for (int m = 16; m >= 1; m >>= 1) { ps += __shfl_xor(ps, m); pd += __shfl_xor(pd, m); }
            if (n < NN) {
                h1b[n * 128 + j] = __float2bfloat16(v);
                if ((j & 31) == 0) { asrc1[n * 4 + h] = ps; adst1[n * 4 + h] = pd; }
            }
        }
    }
}

// ---------------- layer-1 logits, edge-parallel, log2e-scaled ----------------
__global__ void k_z1(const int* __restrict__ bsrc, const int* __restrict__ bdst,
                     const float* __restrict__ battr,
                     const float* __restrict__ asrc1, const float* __restrict__ adst1,
                     const float* __restrict__ cbuf, float* z1) {
    int p = blockIdx.x * 256 + threadIdx.x;
    if (p >= EP) return;
    int s = bsrc[p], d = bdst[p];
    float a = battr[p];
    const float4 vs = *(const float4*)&asrc1[s * 4];
    const float4 vd = *(const float4*)&adst1[d * 4];
    float4 z;
    z.x = vs.x + vd.x + a * cbuf[0];
    z.y = vs.y + vd.y + a * cbuf[1];
    z.z = vs.z + vd.z + a * cbuf[2];
    z.w = vs.w + vd.w + a * cbuf[3];
    z.x = (z.x > 0.f ? z.x : NEG * z.x) * LOG2E;
    z.y = (z.y > 0.f ? z.y : NEG * z.y) * LOG2E;
    z.z = (z.z > 0.f ? z.z : NEG * z.z) * LOG2E;
    z.w = (z.w > 0.f ? z.w : NEG * z.w) * LOG2E;
    *(float4*)&z1[(size_t)p * 4] = z;
}

// ---------------- layer-1 two-pass softmax+aggregate: one wave per node ----------------
__global__ void k_gat1(const int* __restrict__ rowptr, const int* __restrict__ bsrc,
                       const float* __restrict__ z1, const uint* __restrict__ h1u,
                       float* out1) {
    int wid = (blockIdx.x * 256 + threadIdx.x) >> 6;   // one wave per node
    if (wid >= NN) return;
    int lane = threadIdx.x & 63;
    int p0 = rowptr[wid], p1 = rowptr[wid + 1];
    // pass A: lane-parallel componentwise max over the node's edges
    float4 m4 = make_float4(-INFINITY, -INFINITY, -INFINITY, -INFINITY);
    for (int p = p0 + lane; p < p1; p += 64) {
        const float4 z = *(const float4*)&z1[(size_t)p * 4];
        m4.x = fmaxf(m4.x, z.x); m4.y = fmaxf(m4.y, z.y);
        m4.z = fmaxf(m4.z, z.z); m4.w = fmaxf(m4.w, z.w);
    }
    #pragma unroll
    for (int k = 32; k >= 1; k >>= 1) {
        m4.x = fmaxf(m4.x, __shfl_xor(m4.x, k));
        m4.y = fmaxf(m4.y, __shfl_xor(m4.y, k));
        m4.z = fmaxf(m4.z, __shfl_xor(m4.z, k));
        m4.w = fmaxf(m4.w, __shfl_xor(m4.w, k));
    }
    int h = lane >> 4;
    float m = (h == 0) ? m4.x : (h == 1) ? m4.y : (h == 2) ? m4.z : m4.w;
    // pass B: native exp2 + bf16x2 gather (4B/lane), 32-bit addressing, unroll 4
    float s = 0.f, acc0 = 0.f, acc1 = 0.f;
    int p = p0;
    for (; p + 4 <= p1; p += 4) {
        float z0 = z1[p * 4 + h],       z1v = z1[(p + 1) * 4 + h];
        float z2v = z1[(p + 2) * 4 + h], z3v = z1[(p + 3) * 4 + h];
        int s0 = bsrc[p], s1 = bsrc[p + 1], s2 = bsrc[p + 2], s3 = bsrc[p + 3];
        uint u0 = h1u[s0 * 64 + lane];
        uint u1 = h1u[s1 * 64 + lane];
        uint u2 = h1u[s2 * 64 + lane];
        uint u3 = h1u[s3 * 64 + lane];
        float w0 = exp2f(z0 - m), w1 = exp2f(z1v - m);
        float w2 = exp2f(z2v - m), w3 = exp2f(z3v - m);
        s += (w0 + w1) + (w2 + w3);
        acc0 += w0 * __uint_as_float(u0 << 16) + w1 * __uint_as_float(u1 << 16)
              + w2 * __uint_as_float(u2 << 16) + w3 * __uint_as_float(u3 << 16);
        acc1 += w0 * __uint_as_float(u0 & 0xffff0000u) + w1 * __uint_as_float(u1 & 0xffff0000u)
              + w2 * __uint_as_float(u2 & 0xffff0000u) + w3 * __uint_as_float(u3 & 0xffff0000u);
    }
    for (; p < p1; ++p) {
        float z = z1[p * 4 + h];
        int s0 = bsrc[p];
        float w = exp2f(z - m);
        uint u0 = h1u[s0 * 64 + lane];
        s += w;
        acc0 += w * __uint_as_float(u0 << 16);
        acc1 += w * __uint_as_float(u0 & 0xffff0000u);
    }
    float inv = 1.f / s;
    float2 o; o.x = acc0 * inv; o.y = acc1 * inv;
    *(float2*)&out1[(size_t)wid * 128 + lane * 2] = o;
}

// ---------------- h2 = elu(out1 + b1) @ W2  [N,32] (bf16 store); layer-2 att dots ----------------
__global__ void k_h2(const float* __restrict__ out1, const float* __restrict__ b1,
                     const float* __restrict__ W2,
                     const float* __restrict__ as2, const float* __restrict__ ad2,
                     __hip_bfloat16* h2b, float* asrc2, float* adst2) {
    __shared__ float sW[128 * 32];
    __shared__ float sx[8][128];
    int tid = threadIdx.x;             // 256
    for (int i = tid; i < 128 * 32; i += 256) sW[i] = W2[i];
    int nl = tid >> 5, j = tid & 31;
    int base = blockIdx.x * 32;
    float es = as2[j], ed = ad2[j];
    for (int it = 0; it < 4; ++it) {
        int n0 = base + it * 8;
        __syncthreads();
        for (int i = tid; i < 1024; i += 256) {
            int r = i >> 7, k = i & 127;
            int n = n0 + r;
            float v = (n < NN) ? out1[(size_t)n * 128 + k] + b1[k] : 0.f;
            sx[r][k] = v > 0.f ? v : expm1f(v);
        }
        __syncthreads();
        int n = n0 + nl;
        float acc = 0.f;
        #pragma unroll 8
        for (int k = 0; k < 128; ++k) acc += sx[nl][k] * sW[k * 32 + j];
        float ps = acc * es, pd = acc * ed;
        #pragma unroll
        for (int m = 16; m >= 1; m >>= 1) { ps += __shfl_xor(ps, m); pd += __shfl_xor(pd, m); }
        if (n < NN) {
            h2b[n * 32 + j] = __float2bfloat16(acc);
            if (j == 0) { asrc2[n] = ps; adst2[n] = pd; }
        }
    }
}

// ---------------- layer-2 logits, edge-parallel, log2e-scaled ----------------
__global__ void k_z2(const int* __restrict__ bsrc, const int* __restrict__ bdst,
                     const float* __restrict__ battr,
                     const float* __restrict__ asrc2, const float* __restrict__ adst2,
                     const float* __restrict__ cbuf, float* z2) {
    int p = blockIdx.x * 256 + threadIdx.x;
    if (p >= EP) return;
    float z = asrc2[bsrc[p]] + adst2[bdst[p]] + battr[p] * cbuf[4];
    z = z > 0.f ? z : NEG * z;
    z2[p] = z * LOG2E;
}

// ---------------- layer-2 two-pass softmax+aggregate: one wave per node ----------------
__global__ void k_gat2(const int* __restrict__ rowptr, const int* __restrict__ bsrc,
                       const float* __restrict__ z2, const __hip_bfloat16* __restrict__ h2b,
                       const float* __restrict__ b2, float* dout) {
    int wid = (blockIdx.x * 256 + threadIdx.x) >> 6;   // one wave per node
    if (wid >= NN) return;
    int lane = threadIdx.x & 63;
    int j = lane & 31, eo = lane >> 5;
    int p0 = rowptr[wid], p1 = rowptr[wid + 1];
    // pass A: lane-parallel max
    float m = -INFINITY;
    for (int p = p0 + lane; p < p1; p += 64) m = fmaxf(m, z2[p]);
    #pragma unroll
    for (int k = 32; k >= 1; k >>= 1) m = fmaxf(m, __shfl_xor(m, k));
    // pass B: 4 edges per wave-iter (2 per half), bf16 gather
    float s = 0.f, acc = 0.f;
    int p = p0 + eo;
    for (; p + 2 < p1; p += 4) {
        float wA = exp2f(z2[p] - m), wB = exp2f(z2[p + 2] - m);
        int sA = bsrc[p], sB = bsrc[p + 2];
        float hA = __bfloat162float(h2b[sA * 32 + j]);
        float hB = __bfloat162float(h2b[sB * 32 + j]);
        s += wA + wB;
        acc += wA * hA + wB * hB;
    }
    if (p < p1) {
        float w = exp2f(z2[p] - m);
        int src = bsrc[p];
        s += w;
        acc += w * __bfloat162float(h2b[src * 32 + j]);
    }
    s += __shfl_xor(s, 32);
    acc += __shfl_xor(acc, 32);
    if (eo == 0) dout[(size_t)wid * 32 + j] = acc / s + b2[j];
}

extern "C" void kernel_launch(void* const* d_in, const int* in_sizes, int n_in,
                              void* d_out, int out_size, void* d_ws, size_t ws_size,
                              hipStream_t stream) {
    const float* x     = (const float*)d_in[0];
    const int*   ei    = (const int*)d_in[1];
    const float* eattr = (const float*)d_in[2];
    const float* W1    = (const float*)d_in[3];
    const float* as1   = (const float*)d_in[4];
    const float* ad1   = (const float*)d_in[5];
    const float* We1   = (const float*)d_in[6];
    const float* ae1   = (const float*)d_in[7];
    const float* b1    = (const float*)d_in[8];
    const float* W2    = (const float*)d_in[9];
    const float* as2   = (const float*)d_in[10];
    const float* ad2   = (const float*)d_in[11];
    const float* We2   = (const float*)d_in[12];
    const float* ae2   = (const float*)d_in[13];
    const float* b2    = (const float*)d_in[14];
    float* dout = (float*)d_out;

    char* p = (char*)d_ws;
    int*   degi   = (int*)p;   p += sizeof(int) * NN;
    float* asum   = (float*)p; p += sizeof(float) * NN;
    int*   rowptr = (int*)p;   p += sizeof(int) * (NN + 4);
    int*   cursor = (int*)p;   p += sizeof(int) * NN;
    int*   blksum = (int*)p;   p += sizeof(int) * 256;
    int*   bsrc   = (int*)p;   p += sizeof(int) * EP;
    int*   bdst   = (int*)p;   p += sizeof(int) * EP;
    float* battr  = (float*)p; p += sizeof(float) * EP;
    float* z1     = (float*)p; p += sizeof(float) * (size_t)EP * 4;  // 16B-aligned
    __hip_bfloat16* h1b = (__hip_bfloat16*)p; p += sizeof(__hip_bfloat16) * (size_t)NN * 128;
    float* asrc1  = (float*)p; p += sizeof(float) * NN * 4;
    float* adst1  = (float*)p; p += sizeof(float) * NN * 4;
    float* out1   = (float*)p; p += sizeof(float) * (size_t)NN * 128;
    __hip_bfloat16* h2b = (__hip_bfloat16*)p; p += sizeof(__hip_bfloat16) * NN * 32;
    float* asrc2  = (float*)p; p += sizeof(float) * NN;
    float* adst2  = (float*)p; p += sizeof(float) * NN;
    float* cbuf   = (float*)p; p += sizeof(float) * 8;
    float* z2     = z1;   // reuse: z1 dead after k_gat1

    k_zero   <<<(NN + 255) / 256, 256, 0, stream>>>(degi, asum);
    k_const  <<<1, 128, 0, stream>>>(We1, ae1, We2, ae2, cbuf);
    k_degi   <<<(EE + 255) / 256, 256, 0, stream>>>(ei, eattr, degi, asum);
    k_scan1  <<<NB, 256, 0, stream>>>(degi, rowptr, blksum);
    k_scan2  <<<1, 256, 0, stream>>>(blksum);
    k_scan3  <<<NB, 256, 0, stream>>>(degi, asum, rowptr, blksum, cursor, bsrc, bdst, battr);
    k_scatter<<<(EE + 255) / 256, 256, 0, stream>>>(ei, eattr, cursor, bsrc, bdst, battr);
    k_h1     <<<(NN + 15) / 16, 128, 0, stream>>>(x, W1, as1, ad1, h1b, asrc1, adst1);
    k_z1     <<<(EP + 255) / 256, 256, 0, stream>>>(bsrc, bdst, battr, asrc1, adst1, cbuf, z1);
    k_gat1   <<<(NN * 64 + 255) / 256, 256, 0, stream>>>(rowptr, bsrc, z1, (const uint*)h1b, out1);
    k_h2     <<<(NN + 31) / 32, 256, 0, stream>>>(out1, b1, W2, as2, ad2, h2b, asrc2, adst2);
    k_z2     <<<(EP + 255) / 256, 256, 0, stream>>>(bsrc, bdst, battr, asrc2, adst2, cbuf, z2);
    k_gat2   <<<(NN * 64 + 255) / 256, 256, 0, stream>>>(rowptr, bsrc, z2, h2b, b2, dout);
}

// Round 14
// 377.709 us; speedup vs baseline: 2.9716x; 1.1043x over previous
//
#include <hip/hip_runtime.h>
#include <hip/hip_bf16.h>
#include <math.h>

#define NN 50000
#define EE 800000
#define EP 850000   /* EE + NN self loops */
#define NB 196      /* (NN+255)/256 scan blocks */
#define NHIST 8     /* privatized degree-histogram copies (~per-XCD) */
#define HPAD 50048  /* NN padded to 64 */
#define NEG 0.2f
#define LOG2E 1.4426950408889634f

// ---------------- zero the 8 privatized degree histograms ----------------
__global__ void k_zero(int* hist) {
    int i = blockIdx.x * 256 + threadIdx.x;
    if (i < NHIST * HPAD) hist[i] = 0;
}

// ---------------- edge-scalar constants ce1[4], ce2 ----------------
__global__ void k_const(const float* __restrict__ We1, const float* __restrict__ ae1,
                        const float* __restrict__ We2, const float* __restrict__ ae2,
                        float* cbuf) {
    int j = threadIdx.x;               // 128 threads
    float p = We1[j] * ae1[j];
    #pragma unroll
    for (int m = 16; m >= 1; m >>= 1) p += __shfl_xor(p, m);
    if ((j & 31) == 0) cbuf[j >> 5] = p;
    if (j < 32) {
        float q = We2[j] * ae2[j];
        #pragma unroll
        for (int m = 16; m >= 1; m >>= 1) q += __shfl_xor(q, m);
        if (j == 0) cbuf[4] = q;
    }
}

// ---------------- degree count into per-(blockIdx&7) privatized histogram ----------------
__global__ void k_degi(const int* __restrict__ ei, int* hist) {
    int e = blockIdx.x * 256 + threadIdx.x;
    if (e >= EE) return;
    int d = ei[EE + e];
    atomicAdd(&hist[(blockIdx.x & 7) * HPAD + d], 1);
}

// ---------------- hierarchical scan over deg+1 (merging 8 hist copies) ----------------
__global__ void k_scan1(const int* __restrict__ hist, int* rowptr, int* blksum) {
    __shared__ int part[256];
    int t = threadIdx.x;
    int i = blockIdx.x * 256 + t;
    int dg = 0;
    if (i < NN) {
        #pragma unroll
        for (int c = 0; c < NHIST; ++c) dg += hist[c * HPAD + i];
    }
    int v = (i < NN) ? dg + 1 : 0;
    part[t] = v;
    __syncthreads();
    #pragma unroll
    for (int d = 1; d < 256; d <<= 1) {
        int u = (t >= d) ? part[t - d] : 0;
        __syncthreads();
        part[t] += u;
        __syncthreads();
    }
    if (i < NN) rowptr[i] = part[t] - v;          // local exclusive prefix
    if (t == 255) blksum[blockIdx.x] = part[255]; // block total
}

__global__ void k_scan2(int* blksum) {
    __shared__ int part[256];
    int t = threadIdx.x;
    int v = (t < NB) ? blksum[t] : 0;
    part[t] = v;
    __syncthreads();
    #pragma unroll
    for (int d = 1; d < 256; d <<= 1) {
        int u = (t >= d) ? part[t - d] : 0;
        __syncthreads();
        part[t] += u;
        __syncthreads();
    }
    if (t < NB) blksum[t] = part[t] - v;          // exclusive block offsets
}

__global__ void k_scan3(int* rowptr, const int* __restrict__ blksum,
                        int* cursor, int* bsrc, int* bdst) {
    int i = blockIdx.x * 256 + threadIdx.x;
    if (i >= NN) return;
    int off = rowptr[i] + blksum[blockIdx.x];
    rowptr[i] = off;
    bsrc[off] = i;                                 // self-loop first in segment
    bdst[off] = i;
    cursor[i] = off + 1;
    if (i == 0) rowptr[NN] = EP;
}

// ---------------- scatter real edges into CSR buckets ----------------
__global__ void k_scatter(const int* __restrict__ ei, const float* __restrict__ eattr,
                          int* cursor, int* bsrc, int* bdst, float* battr) {
    int e = blockIdx.x * 256 + threadIdx.x;
    if (e >= EE) return;
    int d = ei[EE + e];
    int p = atomicAdd(&cursor[d], 1);
    bsrc[p] = ei[e];
    bdst[p] = d;
    battr[p] = eattr[e];
}

// ---------------- self-loop attr = mean of incoming battr (no atomics) ----------------
__global__ void k_loopattr(const int* __restrict__ rowptr, float* battr) {
    int i = blockIdx.x * 256 + threadIdx.x;
    if (i >= NN) return;
    int p0 = rowptr[i], p1 = rowptr[i + 1];
    float s = 0.f;
    for (int p = p0 + 1; p < p1; ++p) s += battr[p];
    battr[p0] = s / fmaxf((float)(p1 - p0 - 1), 1.f);  // PyG fill_value='mean'
}

// ---------------- h1 = x @ W1  [N,128] (bf16 store); per-head att dots (fp32) ----------------
__global__ void k_h1(const float* __restrict__ x, const float* __restrict__ W1,
                     const float* __restrict__ as1, const float* __restrict__ ad1,
                     __hip_bfloat16* h1b, float* asrc1, float* adst1) {
    __shared__ float sx[4][128];
    int j = threadIdx.x;               // 128 threads, j = output column
    int base = blockIdx.x * 16;
    int h = j >> 5;
    float es = as1[j];
    float ed = ad1[j];
    for (int it = 0; it < 4; ++it) {
        int n0 = base + it * 4;
        __syncthreads();
        #pragma unroll
        for (int r = 0; r < 4; ++r) {
            int n = n0 + r;
            sx[r][j] = (n < NN) ? x[(size_t)n * 128 + j] : 0.f;
        }
        __syncthreads();
        float a0 = 0.f, a1 = 0.f, a2 = 0.f, a3 = 0.f;
        #pragma unroll 8
        for (int k = 0; k < 128; ++k) {
            float w = W1[k * 128 + j];
            a0 += sx[0][k] * w; a1 += sx[1][k] * w;
            a2 += sx[2][k] * w; a3 += sx[3][k] * w;
        }
        float accs[4] = {a0, a1, a2, a3};
        #pragma unroll
        for (int r = 0; r < 4; ++r) {
            int n = n0 + r;
            float v = accs[r];
            float ps = v * es, pd = v * ed;
            #pragma unroll
            for (int m = 16; m >= 1; m >>= 1) { ps += __shfl_xor(ps, m); pd += __shfl_xor(pd, m); }
            if (n < NN) {
                h1b[n * 128 + j] = __float2bfloat16(v);
                if ((j & 31) == 0) { asrc1[n * 4 + h] = ps; adst1[n * 4 + h] = pd; }
            }
        }
    }
}

// ---------------- layer-1 logits, edge-parallel, log2e-scaled ----------------
__global__ void k_z1(const int* __restrict__ bsrc, const int* __restrict__ bdst,
                     const float* __restrict__ battr,
                     const float* __restrict__ asrc1, const float* __restrict__ adst1,
                     const float* __restrict__ cbuf, float* z1) {
    int p = blockIdx.x * 256 + threadIdx.x;
    if (p >= EP) return;
    int s = bsrc[p], d = bdst[p];
    float a = battr[p];
    const float4 vs = *(const float4*)&asrc1[s * 4];
    const float4 vd = *(const float4*)&adst1[d * 4];
    float4 z;
    z.x = vs.x + vd.x + a * cbuf[0];
    z.y = vs.y + vd.y + a * cbuf[1];
    z.z = vs.z + vd.z + a * cbuf[2];
    z.w = vs.w + vd.w + a * cbuf[3];
    z.x = (z.x > 0.f ? z.x : NEG * z.x) * LOG2E;
    z.y = (z.y > 0.f ? z.y : NEG * z.y) * LOG2E;
    z.z = (z.z > 0.f ? z.z : NEG * z.z) * LOG2E;
    z.w = (z.w > 0.f ? z.w : NEG * z.w) * LOG2E;
    *(float4*)&z1[(size_t)p * 4] = z;
}

// ---------------- layer-1 two-pass softmax+aggregate: one wave per node ----------------
__global__ void k_gat1(const int* __restrict__ rowptr, const int* __restrict__ bsrc,
                       const float* __restrict__ z1, const uint* __restrict__ h1u,
                       float* out1) {
    int wid = (blockIdx.x * 256 + threadIdx.x) >> 6;   // one wave per node
    if (wid >= NN) return;
    int lane = threadIdx.x & 63;
    int p0 = rowptr[wid], p1 = rowptr[wid + 1];
    // pass A: lane-parallel componentwise max over the node's edges
    float4 m4 = make_float4(-INFINITY, -INFINITY, -INFINITY, -INFINITY);
    for (int p = p0 + lane; p < p1; p += 64) {
        const float4 z = *(const float4*)&z1[(size_t)p * 4];
        m4.x = fmaxf(m4.x, z.x); m4.y = fmaxf(m4.y, z.y);
        m4.z = fmaxf(m4.z, z.z); m4.w = fmaxf(m4.w, z.w);
    }
    #pragma unroll
    for (int k = 32; k >= 1; k >>= 1) {
        m4.x = fmaxf(m4.x, __shfl_xor(m4.x, k));
        m4.y = fmaxf(m4.y, __shfl_xor(m4.y, k));
        m4.z = fmaxf(m4.z, __shfl_xor(m4.z, k));
        m4.w = fmaxf(m4.w, __shfl_xor(m4.w, k));
    }
    int h = lane >> 4;
    float m = (h == 0) ? m4.x : (h == 1) ? m4.y : (h == 2) ? m4.z : m4.w;
    // pass B: native exp2 + bf16x2 gather (4B/lane), 32-bit addressing, unroll 4
    float s = 0.f, acc0 = 0.f, acc1 = 0.f;
    int p = p0;
    for (; p + 4 <= p1; p += 4) {
        float z0 = z1[p * 4 + h],       z1v = z1[(p + 1) * 4 + h];
        float z2v = z1[(p + 2) * 4 + h], z3v = z1[(p + 3) * 4 + h];
        int s0 = bsrc[p], s1 = bsrc[p + 1], s2 = bsrc[p + 2], s3 = bsrc[p + 3];
        uint u0 = h1u[s0 * 64 + lane];
        uint u1 = h1u[s1 * 64 + lane];
        uint u2 = h1u[s2 * 64 + lane];
        uint u3 = h1u[s3 * 64 + lane];
        float w0 = exp2f(z0 - m), w1 = exp2f(z1v - m);
        float w2 = exp2f(z2v - m), w3 = exp2f(z3v - m);
        s += (w0 + w1) + (w2 + w3);
        acc0 += w0 * __uint_as_float(u0 << 16) + w1 * __uint_as_float(u1 << 16)
              + w2 * __uint_as_float(u2 << 16) + w3 * __uint_as_float(u3 << 16);
        acc1 += w0 * __uint_as_float(u0 & 0xffff0000u) + w1 * __uint_as_float(u1 & 0xffff0000u)
              + w2 * __uint_as_float(u2 & 0xffff0000u) + w3 * __uint_as_float(u3 & 0xffff0000u);
    }
    for (; p < p1; ++p) {
        float z = z1[p * 4 + h];
        int s0 = bsrc[p];
        float w = exp2f(z - m);
        uint u0 = h1u[s0 * 64 + lane];
        s += w;
        acc0 += w * __uint_as_float(u0 << 16);
        acc1 += w * __uint_as_float(u0 & 0xffff0000u);
    }
    float inv = 1.f / s;
    float2 o; o.x = acc0 * inv; o.y = acc1 * inv;
    *(float2*)&out1[(size_t)wid * 128 + lane * 2] = o;
}

// ---------------- h2 = elu(out1 + b1) @ W2  [N,32] (bf16 store); layer-2 att dots ----------------
__global__ void k_h2(const float* __restrict__ out1, const float* __restrict__ b1,
                     const float* __restrict__ W2,
                     const float* __restrict__ as2, const float* __restrict__ ad2,
                     __hip_bfloat16* h2b, float* asrc2, float* adst2) {
    __shared__ float sW[128 * 32];
    __shared__ float sx[8][128];
    int tid = threadIdx.x;             // 256
    for (int i = tid; i < 128 * 32; i += 256) sW[i] = W2[i];
    int nl = tid >> 5, j = tid & 31;
    int base = blockIdx.x * 32;
    float es = as2[j], ed = ad2[j];
    for (int it = 0; it < 4; ++it) {
        int n0 = base + it * 8;
        __syncthreads();
        for (int i = tid; i < 1024; i += 256) {
            int r = i >> 7, k = i & 127;
            int n = n0 + r;
            float v = (n < NN) ? out1[(size_t)n * 128 + k] + b1[k] : 0.f;
            sx[r][k] = v > 0.f ? v : expm1f(v);
        }
        __syncthreads();
        int n = n0 + nl;
        float acc = 0.f;
        #pragma unroll 8
        for (int k = 0; k < 128; ++k) acc += sx[nl][k] * sW[k * 32 + j];
        float ps = acc * es, pd = acc * ed;
        #pragma unroll
        for (int m = 16; m >= 1; m >>= 1) { ps += __shfl_xor(ps, m); pd += __shfl_xor(pd, m); }
        if (n < NN) {
            h2b[n * 32 + j] = __float2bfloat16(acc);
            if (j == 0) { asrc2[n] = ps; adst2[n] = pd; }
        }
    }
}

// ---------------- layer-2 logits, edge-parallel, log2e-scaled ----------------
__global__ void k_z2(const int* __restrict__ bsrc, const int* __restrict__ bdst,
                     const float* __restrict__ battr,
                     const float* __restrict__ asrc2, const float* __restrict__ adst2,
                     const float* __restrict__ cbuf, float* z2) {
    int p = blockIdx.x * 256 + threadIdx.x;
    if (p >= EP) return;
    float z = asrc2[bsrc[p]] + adst2[bdst[p]] + battr[p] * cbuf[4];
    z = z > 0.f ? z : NEG * z;
    z2[p] = z * LOG2E;
}

// ---------------- layer-2 two-pass softmax+aggregate: one wave per node ----------------
__global__ void k_gat2(const int* __restrict__ rowptr, const int* __restrict__ bsrc,
                       const float* __restrict__ z2, const __hip_bfloat16* __restrict__ h2b,
                       const float* __restrict__ b2, float* dout) {
    int wid = (blockIdx.x * 256 + threadIdx.x) >> 6;   // one wave per node
    if (wid >= NN) return;
    int lane = threadIdx.x & 63;
    int j = lane & 31, eo = lane >> 5;
    int p0 = rowptr[wid], p1 = rowptr[wid + 1];
    // pass A: lane-parallel max
    float m = -INFINITY;
    for (int p = p0 + lane; p < p1; p += 64) m = fmaxf(m, z2[p]);
    #pragma unroll
    for (int k = 32; k >= 1; k >>= 1) m = fmaxf(m, __shfl_xor(m, k));
    // pass B: 4 edges per wave-iter (2 per half), bf16 gather
    float s = 0.f, acc = 0.f;
    int p = p0 + eo;
    for (; p + 2 < p1; p += 4) {
        float wA = exp2f(z2[p] - m), wB = exp2f(z2[p + 2] - m);
        int sA = bsrc[p], sB = bsrc[p + 2];
        float hA = __bfloat162float(h2b[sA * 32 + j]);
        float hB = __bfloat162float(h2b[sB * 32 + j]);
        s += wA + wB;
        acc += wA * hA + wB * hB;
    }
    if (p < p1) {
        float w = exp2f(z2[p] - m);
        int src = bsrc[p];
        s += w;
        acc += w * __bfloat162float(h2b[src * 32 + j]);
    }
    s += __shfl_xor(s, 32);
    acc += __shfl_xor(acc, 32);
    if (eo == 0) dout[(size_t)wid * 32 + j] = acc / s + b2[j];
}

extern "C" void kernel_launch(void* const* d_in, const int* in_sizes, int n_in,
                              void* d_out, int out_size, void* d_ws, size_t ws_size,
                              hipStream_t stream) {
    const float* x     = (const float*)d_in[0];
    const int*   ei    = (const int*)d_in[1];
    const float* eattr = (const float*)d_in[2];
    const float* W1    = (const float*)d_in[3];
    const float* as1   = (const float*)d_in[4];
    const float* ad1   = (const float*)d_in[5];
    const float* We1   = (const float*)d_in[6];
    const float* ae1   = (const float*)d_in[7];
    const float* b1    = (const float*)d_in[8];
    const float* W2    = (const float*)d_in[9];
    const float* as2   = (const float*)d_in[10];
    const float* ad2   = (const float*)d_in[11];
    const float* We2   = (const float*)d_in[12];
    const float* ae2   = (const float*)d_in[13];
    const float* b2    = (const float*)d_in[14];
    float* dout = (float*)d_out;

    char* p = (char*)d_ws;
    int*   hist   = (int*)p;   p += sizeof(int) * NHIST * HPAD;
    int*   rowptr = (int*)p;   p += sizeof(int) * (NN + 4);
    int*   cursor = (int*)p;   p += sizeof(int) * NN;
    int*   blksum = (int*)p;   p += sizeof(int) * 256;
    int*   bsrc   = (int*)p;   p += sizeof(int) * EP;
    int*   bdst   = (int*)p;   p += sizeof(int) * EP;
    float* battr  = (float*)p; p += sizeof(float) * EP;
    float* z1     = (float*)p; p += sizeof(float) * (size_t)EP * 4;  // 16B-aligned
    __hip_bfloat16* h1b = (__hip_bfloat16*)p; p += sizeof(__hip_bfloat16) * (size_t)NN * 128;
    float* asrc1  = (float*)p; p += sizeof(float) * NN * 4;
    float* adst1  = (float*)p; p += sizeof(float) * NN * 4;
    float* out1   = (float*)p; p += sizeof(float) * (size_t)NN * 128;
    __hip_bfloat16* h2b = (__hip_bfloat16*)p; p += sizeof(__hip_bfloat16) * NN * 32;
    float* asrc2  = (float*)p; p += sizeof(float) * NN;
    float* adst2  = (float*)p; p += sizeof(float) * NN;
    float* cbuf   = (float*)p; p += sizeof(float) * 8;
    float* z2     = z1;   // reuse: z1 dead after k_gat1

    k_zero    <<<(NHIST * HPAD + 255) / 256, 256, 0, stream>>>(hist);
    k_const   <<<1, 128, 0, stream>>>(We1, ae1, We2, ae2, cbuf);
    k_degi    <<<(EE + 255) / 256, 256, 0, stream>>>(ei, hist);
    k_scan1   <<<NB, 256, 0, stream>>>(hist, rowptr, blksum);
    k_scan2   <<<1, 256, 0, stream>>>(blksum);
    k_scan3   <<<NB, 256, 0, stream>>>(rowptr, blksum, cursor, bsrc, bdst);
    k_scatter <<<(EE + 255) / 256, 256, 0, stream>>>(ei, eattr, cursor, bsrc, bdst, battr);
    k_loopattr<<<(NN + 255) / 256, 256, 0, stream>>>(rowptr, battr);
    k_h1      <<<(NN + 15) / 16, 128, 0, stream>>>(x, W1, as1, ad1, h1b, asrc1, adst1);
    k_z1      <<<(EP + 255) / 256, 256, 0, stream>>>(bsrc, bdst, battr, asrc1, adst1, cbuf, z1);
    k_gat1    <<<(NN * 64 + 255) / 256, 256, 0, stream>>>(rowptr, bsrc, z1, (const uint*)h1b, out1);
    k_h2      <<<(NN + 31) / 32, 256, 0, stream>>>(out1, b1, W2, as2, ad2, h2b, asrc2, adst2);
    k_z2      <<<(EP + 255) / 256, 256, 0, stream>>>(bsrc, bdst, battr, asrc2, adst2, cbuf, z2);
    k_gat2    <<<(NN * 64 + 255) / 256, 256, 0, stream>>>(rowptr, bsrc, z2, h2b, b2, dout);
}

// Round 15
// 366.865 us; speedup vs baseline: 3.0594x; 1.0296x over previous
//
#include <hip/hip_runtime.h>
#include <hip/hip_bf16.h>
#include <math.h>

#define NN 50000
#define EE 800000
#define EP 850000   /* EE + NN self loops */
#define NB 196      /* (NN+255)/256 scan blocks */
#define NHIST 8     /* privatized histogram/cursor copies (~per-XCD) */
#define HPAD 50048  /* NN padded to 64 */
#define NEG 0.2f
#define LOG2E 1.4426950408889634f

// ---------------- zero the 8 privatized degree histograms ----------------
__global__ void k_zero(int* hist) {
    int i = blockIdx.x * 256 + threadIdx.x;
    if (i < NHIST * HPAD) hist[i] = 0;
}

// ---------------- edge-scalar constants ce1[4], ce2 (pre-scaled by log2e) ----------------
__global__ void k_const(const float* __restrict__ We1, const float* __restrict__ ae1,
                        const float* __restrict__ We2, const float* __restrict__ ae2,
                        float* cbuf) {
    int j = threadIdx.x;               // 128 threads
    float p = We1[j] * ae1[j];
    #pragma unroll
    for (int m = 16; m >= 1; m >>= 1) p += __shfl_xor(p, m);
    if ((j & 31) == 0) cbuf[j >> 5] = p * LOG2E;
    if (j < 32) {
        float q = We2[j] * ae2[j];
        #pragma unroll
        for (int m = 16; m >= 1; m >>= 1) q += __shfl_xor(q, m);
        if (j == 0) cbuf[4] = q * LOG2E;
    }
}

// ---------------- degree count into per-(blockIdx&7) privatized histogram ----------------
__global__ void k_degi(const int* __restrict__ ei, int* hist) {
    int e = blockIdx.x * 256 + threadIdx.x;
    if (e >= EE) return;
    int d = ei[EE + e];
    atomicAdd(&hist[(blockIdx.x & 7) * HPAD + d], 1);
}

// ---------------- hierarchical scan over deg+1 (merging 8 hist copies) ----------------
__global__ void k_scan1(const int* __restrict__ hist, int* rowptr, int* blksum) {
    __shared__ int part[256];
    int t = threadIdx.x;
    int i = blockIdx.x * 256 + t;
    int dg = 0;
    if (i < NN) {
        #pragma unroll
        for (int c = 0; c < NHIST; ++c) dg += hist[c * HPAD + i];
    }
    int v = (i < NN) ? dg + 1 : 0;
    part[t] = v;
    __syncthreads();
    #pragma unroll
    for (int d = 1; d < 256; d <<= 1) {
        int u = (t >= d) ? part[t - d] : 0;
        __syncthreads();
        part[t] += u;
        __syncthreads();
    }
    if (i < NN) rowptr[i] = part[t] - v;          // local exclusive prefix
    if (t == 255) blksum[blockIdx.x] = part[255]; // block total
}

__global__ void k_scan2(int* blksum) {
    __shared__ int part[256];
    int t = threadIdx.x;
    int v = (t < NB) ? blksum[t] : 0;
    part[t] = v;
    __syncthreads();
    #pragma unroll
    for (int d = 1; d < 256; d <<= 1) {
        int u = (t >= d) ? part[t - d] : 0;
        __syncthreads();
        part[t] += u;
        __syncthreads();
    }
    if (t < NB) blksum[t] = part[t] - v;          // exclusive block offsets
}

// ---------------- finalize rowptr; seed self-loop; per-copy sub-segment cursors ----------------
__global__ void k_scan3(int* rowptr, const int* __restrict__ blksum,
                        const int* __restrict__ hist, int* cursor8, uint2* bedge) {
    int i = blockIdx.x * 256 + threadIdx.x;
    if (i >= NN) return;
    int off = rowptr[i] + blksum[blockIdx.x];
    rowptr[i] = off;
    bedge[off] = make_uint2((uint)i, 0u);          // self-loop first; attr patched later
    int cum = off + 1;
    #pragma unroll
    for (int c = 0; c < NHIST; ++c) {              // sub-segment start per scatter copy
        cursor8[c * HPAD + i] = cum;
        cum += hist[c * HPAD + i];
    }
    if (i == 0) rowptr[NN] = EP;
}

// ---------------- scatter real edges: privatized cursor copy, one 8B packed write ----------------
__global__ void k_scatter(const int* __restrict__ ei, const float* __restrict__ eattr,
                          int* cursor8, uint2* bedge) {
    int e = blockIdx.x * 256 + threadIdx.x;        // SAME e->block map as k_degi
    if (e >= EE) return;
    int d = ei[EE + e];
    int p = atomicAdd(&cursor8[(blockIdx.x & 7) * HPAD + d], 1);
    bedge[p] = make_uint2((uint)ei[e], __float_as_uint(eattr[e]));
}

// ---------------- self-loop attr = mean of incoming attrs (no atomics) ----------------
__global__ void k_loopattr(const int* __restrict__ rowptr, uint2* bedge) {
    int i = blockIdx.x * 256 + threadIdx.x;
    if (i >= NN) return;
    int p0 = rowptr[i], p1 = rowptr[i + 1];
    float s = 0.f;
    for (int p = p0 + 1; p < p1; ++p) s += __uint_as_float(bedge[p].y);
    bedge[p0].y = __float_as_uint(s / fmaxf((float)(p1 - p0 - 1), 1.f));  // PyG 'mean'
}

// ---------------- h1 = x @ W1 (bf16 store); att dots (fp32, log2e-scaled) ----------------
__global__ void k_h1(const float* __restrict__ x, const float* __restrict__ W1,
                     const float* __restrict__ as1, const float* __restrict__ ad1,
                     __hip_bfloat16* h1b, float* asrc1, float* adst1) {
    __shared__ float sx[8][128];
    int j = threadIdx.x;               // 128 threads, j = output column
    int base = blockIdx.x * 16;
    int h = j >> 5;
    float es = as1[j];
    float ed = ad1[j];
    for (int it = 0; it < 2; ++it) {   // two 8-row sets: halves W1 traffic vs 4-row
        int n0 = base + it * 8;
        __syncthreads();
        #pragma unroll
        for (int r = 0; r < 8; ++r) {
            int n = n0 + r;
            sx[r][j] = (n < NN) ? x[(size_t)n * 128 + j] : 0.f;
        }
        __syncthreads();
        float a0 = 0.f, a1 = 0.f, a2 = 0.f, a3 = 0.f;
        float a4 = 0.f, a5 = 0.f, a6 = 0.f, a7 = 0.f;
        #pragma unroll 4
        for (int k = 0; k < 128; ++k) {
            float w = W1[k * 128 + j];
            a0 += sx[0][k] * w; a1 += sx[1][k] * w;
            a2 += sx[2][k] * w; a3 += sx[3][k] * w;
            a4 += sx[4][k] * w; a5 += sx[5][k] * w;
            a6 += sx[6][k] * w; a7 += sx[7][k] * w;
        }
        float accs[8] = {a0, a1, a2, a3, a4, a5, a6, a7};
        #pragma unroll
        for (int r = 0; r < 8; ++r) {
            int n = n0 + r;
            float v = accs[r];
            float ps = v * es, pd = v * ed;
            #pragma unroll
            for (int m = 16; m >= 1; m >>= 1) { ps += __shfl_xor(ps, m); pd += __shfl_xor(pd, m); }
            if (n < NN) {
                h1b[n * 128 + j] = __float2bfloat16(v);
                if ((j & 31) == 0) { asrc1[n * 4 + h] = ps * LOG2E; adst1[n * 4 + h] = pd * LOG2E; }
            }
        }
    }
}

// ---------------- layer-1 fused logits+softmax+aggregate: one wave per node ----------------
__global__ void k_gat1(const int* __restrict__ rowptr, const uint2* __restrict__ bedge,
                       const float* __restrict__ asrc1, const float* __restrict__ adst1,
                       const float* __restrict__ cbuf, const uint* __restrict__ h1u,
                       float* out1) {
    int wid = (blockIdx.x * 256 + threadIdx.x) >> 6;   // one wave per node
    if (wid >= NN) return;
    int lane = threadIdx.x & 63;
    int p0 = rowptr[wid], p1 = rowptr[wid + 1];
    const float4 ad4 = *(const float4*)&adst1[wid * 4];   // wave-uniform
    const float4 ce4 = *(const float4*)&cbuf[0];
    // pass A: lane-parallel componentwise max of in-register logits
    float4 m4 = make_float4(-INFINITY, -INFINITY, -INFINITY, -INFINITY);
    for (int p = p0 + lane; p < p1; p += 64) {
        uint2 e = bedge[p];
        float a = __uint_as_float(e.y);
        const float4 as = *(const float4*)&asrc1[e.x * 4];
        float4 z;
        z.x = as.x + ad4.x + a * ce4.x; z.x = z.x > 0.f ? z.x : NEG * z.x;
        z.y = as.y + ad4.y + a * ce4.y; z.y = z.y > 0.f ? z.y : NEG * z.y;
        z.z = as.z + ad4.z + a * ce4.z; z.z = z.z > 0.f ? z.z : NEG * z.z;
        z.w = as.w + ad4.w + a * ce4.w; z.w = z.w > 0.f ? z.w : NEG * z.w;
        m4.x = fmaxf(m4.x, z.x); m4.y = fmaxf(m4.y, z.y);
        m4.z = fmaxf(m4.z, z.z); m4.w = fmaxf(m4.w, z.w);
    }
    #pragma unroll
    for (int k = 32; k >= 1; k >>= 1) {
        m4.x = fmaxf(m4.x, __shfl_xor(m4.x, k));
        m4.y = fmaxf(m4.y, __shfl_xor(m4.y, k));
        m4.z = fmaxf(m4.z, __shfl_xor(m4.z, k));
        m4.w = fmaxf(m4.w, __shfl_xor(m4.w, k));
    }
    int h = lane >> 4;
    float m   = (h == 0) ? m4.x  : (h == 1) ? m4.y  : (h == 2) ? m4.z  : m4.w;
    float adh = (h == 0) ? ad4.x : (h == 1) ? ad4.y : (h == 2) ? ad4.z : ad4.w;
    float ceh = (h == 0) ? ce4.x : (h == 1) ? ce4.y : (h == 2) ? ce4.z : ce4.w;
    // pass B: recompute per-head logit, exp2, bf16x2 gather, unroll 4
    float s = 0.f, acc0 = 0.f, acc1 = 0.f;
    int p = p0;
    for (; p + 4 <= p1; p += 4) {
        uint2 e0 = bedge[p],     e1 = bedge[p + 1];
        uint2 e2 = bedge[p + 2], e3 = bedge[p + 3];
        float q0 = asrc1[e0.x * 4 + h] + adh + __uint_as_float(e0.y) * ceh;
        float q1 = asrc1[e1.x * 4 + h] + adh + __uint_as_float(e1.y) * ceh;
        float q2 = asrc1[e2.x * 4 + h] + adh + __uint_as_float(e2.y) * ceh;
        float q3 = asrc1[e3.x * 4 + h] + adh + __uint_as_float(e3.y) * ceh;
        uint u0 = h1u[e0.x * 64 + lane];
        uint u1 = h1u[e1.x * 64 + lane];
        uint u2 = h1u[e2.x * 64 + lane];
        uint u3 = h1u[e3.x * 64 + lane];
        q0 = q0 > 0.f ? q0 : NEG * q0;  q1 = q1 > 0.f ? q1 : NEG * q1;
        q2 = q2 > 0.f ? q2 : NEG * q2;  q3 = q3 > 0.f ? q3 : NEG * q3;
        float w0 = exp2f(q0 - m), w1 = exp2f(q1 - m);
        float w2 = exp2f(q2 - m), w3 = exp2f(q3 - m);
        s += (w0 + w1) + (w2 + w3);
        acc0 += w0 * __uint_as_float(u0 << 16) + w1 * __uint_as_float(u1 << 16)
              + w2 * __uint_as_float(u2 << 16) + w3 * __uint_as_float(u3 << 16);
        acc1 += w0 * __uint_as_float(u0 & 0xffff0000u) + w1 * __uint_as_float(u1 & 0xffff0000u)
              + w2 * __uint_as_float(u2 & 0xffff0000u) + w3 * __uint_as_float(u3 & 0xffff0000u);
    }
    for (; p < p1; ++p) {
        uint2 e0 = bedge[p];
        float q = asrc1[e0.x * 4 + h] + adh + __uint_as_float(e0.y) * ceh;
        q = q > 0.f ? q : NEG * q;
        float w = exp2f(q - m);
        uint u0 = h1u[e0.x * 64 + lane];
        s += w;
        acc0 += w * __uint_as_float(u0 << 16);
        acc1 += w * __uint_as_float(u0 & 0xffff0000u);
    }
    float inv = 1.f / s;
    float2 o; o.x = acc0 * inv; o.y = acc1 * inv;
    *(float2*)&out1[(size_t)wid * 128 + lane * 2] = o;
}

// ---------------- h2 = elu(out1+b1) @ W2 (bf16 store); dots log2e-scaled ----------------
__global__ void k_h2(const float* __restrict__ out1, const float* __restrict__ b1,
                     const float* __restrict__ W2,
                     const float* __restrict__ as2, const float* __restrict__ ad2,
                     __hip_bfloat16* h2b, float* asrc2, float* adst2) {
    __shared__ float sW[128 * 32];
    __shared__ float sx[8][128];
    int tid = threadIdx.x;             // 256
    for (int i = tid; i < 128 * 32; i += 256) sW[i] = W2[i];
    int nl = tid >> 5, j = tid & 31;
    int base = blockIdx.x * 32;
    float es = as2[j], ed = ad2[j];
    for (int it = 0; it < 4; ++it) {
        int n0 = base + it * 8;
        __syncthreads();
        for (int i = tid; i < 1024; i += 256) {
            int r = i >> 7, k = i & 127;
            int n = n0 + r;
            float v = (n < NN) ? out1[(size_t)n * 128 + k] + b1[k] : 0.f;
            sx[r][k] = v > 0.f ? v : expm1f(v);
        }
        __syncthreads();
        int n = n0 + nl;
        float acc = 0.f;
        #pragma unroll 8
        for (int k = 0; k < 128; ++k) acc += sx[nl][k] * sW[k * 32 + j];
        float ps = acc * es, pd = acc * ed;
        #pragma unroll
        for (int m = 16; m >= 1; m >>= 1) { ps += __shfl_xor(ps, m); pd += __shfl_xor(pd, m); }
        if (n < NN) {
            h2b[n * 32 + j] = __float2bfloat16(acc);
            if (j == 0) { asrc2[n] = ps * LOG2E; adst2[n] = pd * LOG2E; }
        }
    }
}

// ---------------- layer-2 fused logits+softmax+aggregate: one wave per node ----------------
__global__ void k_gat2(const int* __restrict__ rowptr, const uint2* __restrict__ bedge,
                       const float* __restrict__ asrc2, const float* __restrict__ adst2,
                       const float* __restrict__ cbuf, const __hip_bfloat16* __restrict__ h2b,
                       const float* __restrict__ b2, float* dout) {
    int wid = (blockIdx.x * 256 + threadIdx.x) >> 6;   // one wave per node
    if (wid >= NN) return;
    int lane = threadIdx.x & 63;
    int j = lane & 31, eo = lane >> 5;
    int p0 = rowptr[wid], p1 = rowptr[wid + 1];
    float ad = adst2[wid];
    float ce = cbuf[4];
    // pass A: lane-parallel max of in-register logits
    float m = -INFINITY;
    for (int p = p0 + lane; p < p1; p += 64) {
        uint2 e = bedge[p];
        float q = asrc2[e.x] + ad + __uint_as_float(e.y) * ce;
        q = q > 0.f ? q : NEG * q;
        m = fmaxf(m, q);
    }
    #pragma unroll
    for (int k = 32; k >= 1; k >>= 1) m = fmaxf(m, __shfl_xor(m, k));
    // pass B: 4 edges per wave-iter (2 per half), bf16 gather
    float s = 0.f, acc = 0.f;
    int p = p0 + eo;
    for (; p + 2 < p1; p += 4) {
        uint2 eA = bedge[p], eB = bedge[p + 2];
        float qA = asrc2[eA.x] + ad + __uint_as_float(eA.y) * ce;
        float qB = asrc2[eB.x] + ad + __uint_as_float(eB.y) * ce;
        qA = qA > 0.f ? qA : NEG * qA;
        qB = qB > 0.f ? qB : NEG * qB;
        float wA = exp2f(qA - m), wB = exp2f(qB - m);
        float hA = __bfloat162float(h2b[eA.x * 32 + j]);
        float hB = __bfloat162float(h2b[eB.x * 32 + j]);
        s += wA + wB;
        acc += wA * hA + wB * hB;
    }
    if (p < p1) {
        uint2 eA = bedge[p];
        float q = asrc2[eA.x] + ad + __uint_as_float(eA.y) * ce;
        q = q > 0.f ? q : NEG * q;
        float w = exp2f(q - m);
        s += w;
        acc += w * __bfloat162float(h2b[eA.x * 32 + j]);
    }
    s += __shfl_xor(s, 32);
    acc += __shfl_xor(acc, 32);
    if (eo == 0) dout[(size_t)wid * 32 + j] = acc / s + b2[j];
}

extern "C" void kernel_launch(void* const* d_in, const int* in_sizes, int n_in,
                              void* d_out, int out_size, void* d_ws, size_t ws_size,
                              hipStream_t stream) {
    const float* x     = (const float*)d_in[0];
    const int*   ei    = (const int*)d_in[1];
    const float* eattr = (const float*)d_in[2];
    const float* W1    = (const float*)d_in[3];
    const float* as1   = (const float*)d_in[4];
    const float* ad1   = (const float*)d_in[5];
    const float* We1   = (const float*)d_in[6];
    const float* ae1   = (const float*)d_in[7];
    const float* b1    = (const float*)d_in[8];
    const float* W2    = (const float*)d_in[9];
    const float* as2   = (const float*)d_in[10];
    const float* ad2   = (const float*)d_in[11];
    const float* We2   = (const float*)d_in[12];
    const float* ae2   = (const float*)d_in[13];
    const float* b2    = (const float*)d_in[14];
    float* dout = (float*)d_out;

    char* p = (char*)d_ws;
    int*   hist    = (int*)p;   p += sizeof(int) * NHIST * HPAD;
    int*   cursor8 = (int*)p;   p += sizeof(int) * NHIST * HPAD;
    int*   rowptr  = (int*)p;   p += sizeof(int) * (NN + 4);
    int*   blksum  = (int*)p;   p += sizeof(int) * 256;
    uint2* bedge   = (uint2*)p; p += sizeof(uint2) * EP;
    __hip_bfloat16* h1b = (__hip_bfloat16*)p; p += sizeof(__hip_bfloat16) * (size_t)NN * 128;
    float* asrc1   = (float*)p; p += sizeof(float) * NN * 4;
    float* adst1   = (float*)p; p += sizeof(float) * NN * 4;
    float* out1    = (float*)p; p += sizeof(float) * (size_t)NN * 128;
    __hip_bfloat16* h2b = (__hip_bfloat16*)p; p += sizeof(__hip_bfloat16) * NN * 32;
    float* asrc2   = (float*)p; p += sizeof(float) * NN;
    float* adst2   = (float*)p; p += sizeof(float) * NN;
    float* cbuf    = (float*)p; p += sizeof(float) * 8;

    k_zero    <<<(NHIST * HPAD + 255) / 256, 256, 0, stream>>>(hist);
    k_const   <<<1, 128, 0, stream>>>(We1, ae1, We2, ae2, cbuf);
    k_degi    <<<(EE + 255) / 256, 256, 0, stream>>>(ei, hist);
    k_scan1   <<<NB, 256, 0, stream>>>(hist, rowptr, blksum);
    k_scan2   <<<1, 256, 0, stream>>>(blksum);
    k_scan3   <<<NB, 256, 0, stream>>>(rowptr, blksum, hist, cursor8, bedge);
    k_scatter <<<(EE + 255) / 256, 256, 0, stream>>>(ei, eattr, cursor8, bedge);
    k_loopattr<<<(NN + 255) / 256, 256, 0, stream>>>(rowptr, bedge);
    k_h1      <<<(NN + 15) / 16, 128, 0, stream>>>(x, W1, as1, ad1, h1b, asrc1, adst1);
    k_gat1    <<<(NN * 64 + 255) / 256, 256, 0, stream>>>(rowptr, bedge, asrc1, adst1, cbuf, (const uint*)h1b, out1);
    k_h2      <<<(NN + 31) / 32, 256, 0, stream>>>(out1, b1, W2, as2, ad2, h2b, asrc2, adst2);
    k_gat2    <<<(NN * 64 + 255) / 256, 256, 0, stream>>>(rowptr, bedge, asrc2, adst2, cbuf, h2b, b2, dout);
}